// Round 1
// baseline (941.545 us; speedup 1.0000x reference)
//
#include <hip/hip_runtime.h>
#include <hip/hip_bf16.h>
#include <stdint.h>
#include <stddef.h>
#include <math.h>

typedef __bf16 bf8_t __attribute__((ext_vector_type(8)));
typedef __bf16 bf4_t __attribute__((ext_vector_type(4)));
typedef float  f4_t  __attribute__((ext_vector_type(4)));

#define DEV static __device__ __forceinline__

namespace abc {
constexpr int B = 4, T = 2048, D = 1024, H = 4;
constexpr int BT = B * T;          // 8192
constexpr int CH = 64;             // chunk length
constexpr int NC = T / CH;         // 32 chunks
constexpr int BH = B * H;          // 16
constexpr float SCALE = 0.0625f;   // DK^-0.5
constexpr float GN = 16.0f;
constexpr float EPS = 1e-5f;
}

DEV f4_t mfma16(bf8_t a, bf8_t b, f4_t c) {
  return __builtin_amdgcn_mfma_f32_16x16x32_bf16(a, b, c, 0, 0, 0);
}

// ---------------------------------------------------------------------------
// GEMM: C[8192 x 1024] = A[8192 x K] * W[K x 1024] (per blockIdx.z weight)
// 128x128 tile, BK=32, 256 threads (4 waves, 2x2 of 64x64), bf16 MFMA.
// ---------------------------------------------------------------------------
template<bool A_BF16, bool OUT_BF16>
__global__ __launch_bounds__(256)
void gemm_kernel(const void* __restrict__ Ap,
                 const float* __restrict__ w0, const float* __restrict__ w1,
                 const float* __restrict__ w2, const float* __restrict__ w3,
                 const float* __restrict__ w4,
                 void* __restrict__ Cp, int K)
{
  using namespace abc;
  const int z = blockIdx.z;
  const float* Bw = (z == 0) ? w0 : (z == 1) ? w1 : (z == 2) ? w2 : (z == 3) ? w3 : w4;
  const int n0 = blockIdx.x * 128;
  const int m0 = blockIdx.y * 128;
  __shared__ __bf16 As[128][40];   // [m][k], row stride 80B (16B-mult)
  __shared__ __bf16 Bs[128][40];   // [n][k]
  const int tid = threadIdx.x;
  const int lane = tid & 63, wvid = tid >> 6;
  const int wr = wvid >> 1, wc = wvid & 1;
  const int quad = lane >> 4, l16 = lane & 15;
  const f4_t fzero = {0.f, 0.f, 0.f, 0.f};
  f4_t acc[4][4];
  #pragma unroll
  for (int i = 0; i < 4; i++)
    #pragma unroll
    for (int j = 0; j < 4; j++) acc[i][j] = fzero;

  for (int k0 = 0; k0 < K; k0 += 32) {
    __syncthreads();
    if (A_BF16) {
      const __bf16* Ab = (const __bf16*)Ap;
      #pragma unroll
      for (int i = 0; i < 2; i++) {
        int p = tid + 256 * i;               // 512 vec8 chunks: 128 rows x 4
        int row = p >> 2, kq = p & 3;
        *reinterpret_cast<bf8_t*>(&As[row][kq * 8]) =
            *reinterpret_cast<const bf8_t*>(Ab + (size_t)(m0 + row) * K + k0 + kq * 8);
      }
    } else {
      const float* Af = (const float*)Ap;
      #pragma unroll
      for (int i = 0; i < 4; i++) {
        int p = tid + 256 * i;               // 1024 float4: 128 rows x 8
        int row = p >> 3, kq = p & 7;
        float4 v = *reinterpret_cast<const float4*>(Af + (size_t)(m0 + row) * K + k0 + kq * 4);
        __bf16* d = &As[row][kq * 4];
        d[0] = (__bf16)v.x; d[1] = (__bf16)v.y; d[2] = (__bf16)v.z; d[3] = (__bf16)v.w;
      }
    }
    #pragma unroll
    for (int i = 0; i < 4; i++) {
      int p = tid + 256 * i;                 // 1024 float4: 32 k-rows x 32
      int kk = p >> 5, nq = p & 31;
      float4 v = *reinterpret_cast<const float4*>(Bw + (size_t)(k0 + kk) * 1024 + n0 + nq * 4);
      Bs[nq * 4 + 0][kk] = (__bf16)v.x;
      Bs[nq * 4 + 1][kk] = (__bf16)v.y;
      Bs[nq * 4 + 2][kk] = (__bf16)v.z;
      Bs[nq * 4 + 3][kk] = (__bf16)v.w;
    }
    __syncthreads();
    bf8_t af[4], bfv[4];
    #pragma unroll
    for (int i = 0; i < 4; i++)
      af[i] = *reinterpret_cast<const bf8_t*>(&As[wr * 64 + i * 16 + l16][quad * 8]);
    #pragma unroll
    for (int j = 0; j < 4; j++)
      bfv[j] = *reinterpret_cast<const bf8_t*>(&Bs[wc * 64 + j * 16 + l16][quad * 8]);
    #pragma unroll
    for (int i = 0; i < 4; i++)
      #pragma unroll
      for (int j = 0; j < 4; j++)
        acc[i][j] = mfma16(af[i], bfv[j], acc[i][j]);
  }
  const int crow = m0 + wr * 64, ccol = n0 + wc * 64;
  if (OUT_BF16) {
    __bf16* C = (__bf16*)Cp + (size_t)z * BT * 1024;
    #pragma unroll
    for (int i = 0; i < 4; i++)
      #pragma unroll
      for (int j = 0; j < 4; j++)
        #pragma unroll
        for (int r = 0; r < 4; r++)
          C[(size_t)(crow + i * 16 + quad * 4 + r) * 1024 + ccol + j * 16 + l16] =
              (__bf16)acc[i][j][r];
  } else {
    float* C = (float*)Cp;
    #pragma unroll
    for (int i = 0; i < 4; i++)
      #pragma unroll
      for (int j = 0; j < 4; j++)
        #pragma unroll
        for (int r = 0; r < 4; r++)
          C[(size_t)(crow + i * 16 + quad * 4 + r) * 1024 + ccol + j * 16 + l16] =
              acc[i][j][r];
  }
}

// ---------------------------------------------------------------------------
// sg projection: sgl[bh][t] = log_sigmoid(x[b,t,:] . sg_w[:,h]) / 16
// one wave per (b,t), 4 heads per wave
// ---------------------------------------------------------------------------
__global__ __launch_bounds__(256)
void sg_kernel(const float* __restrict__ x, const float* __restrict__ sgw,
               float* __restrict__ sgl)
{
  using namespace abc;
  const int wvid = threadIdx.x >> 6, lane = threadIdx.x & 63;
  const int bt = blockIdx.x * 4 + wvid;
  const float* xr = x + (size_t)bt * 1024;
  float a0 = 0, a1 = 0, a2 = 0, a3 = 0;
  #pragma unroll 4
  for (int u = 0; u < 16; u++) {
    int i = u * 64 + lane;
    float xv = xr[i];
    float4 w = *reinterpret_cast<const float4*>(sgw + (size_t)i * 4);
    a0 += xv * w.x; a1 += xv * w.y; a2 += xv * w.z; a3 += xv * w.w;
  }
  #pragma unroll
  for (int off = 32; off > 0; off >>= 1) {
    a0 += __shfl_down(a0, off);
    a1 += __shfl_down(a1, off);
    a2 += __shfl_down(a2, off);
    a3 += __shfl_down(a3, off);
  }
  if (lane == 0) {
    const int b = bt >> 11, t = bt & (T - 1);
    float r[4] = {a0, a1, a2, a3};
    #pragma unroll
    for (int h = 0; h < 4; h++) {
      float v = r[h];
      float ls = fminf(v, 0.f) - log1pf(expf(-fabsf(v)));
      sgl[(size_t)(b * 4 + h) * T + t] = ls * (1.0f / GN);
    }
  }
}

// ---------------------------------------------------------------------------
// inclusive cumsum over T per (b,h)
// ---------------------------------------------------------------------------
__global__ __launch_bounds__(256)
void scan_kernel(const float* __restrict__ sgl, float* __restrict__ sgc)
{
  using namespace abc;
  const int bh = blockIdx.x;
  const float* in = sgl + (size_t)bh * T;
  float* out = sgc + (size_t)bh * T;
  __shared__ float part[256];
  const int tid = threadIdx.x;
  float v[8]; float s = 0.f;
  #pragma unroll
  for (int i = 0; i < 8; i++) { v[i] = in[tid * 8 + i]; s += v[i]; }
  part[tid] = s;
  __syncthreads();
  for (int off = 1; off < 256; off <<= 1) {
    float a = (tid >= off) ? part[tid - off] : 0.f;
    __syncthreads();
    part[tid] += a;
    __syncthreads();
  }
  float run = (tid > 0) ? part[tid - 1] : 0.f;
  #pragma unroll
  for (int i = 0; i < 8; i++) { run += v[i]; out[tid * 8 + i] = run; }
}

// ---------------------------------------------------------------------------
// prep: RoPE(q), RoPE(k)*exp(cumsum sg), s -> exp(clamp(s)) ; in-place on bf16
// one block per (b,t) row
// ---------------------------------------------------------------------------
__global__ __launch_bounds__(256)
void prep_kernel(__bf16* __restrict__ q, __bf16* __restrict__ k,
                 __bf16* __restrict__ s, const float* __restrict__ sgc)
{
  using namespace abc;
  const int bt = blockIdx.x;
  const int b = bt >> 11, t = bt & (T - 1);
  const int tid = threadIdx.x;
  const size_t ro = (size_t)bt * 1024;
  #pragma unroll
  for (int i = 0; i < 2; i++) {
    int p = tid + 256 * i;          // 0..511 : h = p/128, d = p%128
    int h = p >> 7, d = p & 127;
    float inv = expf(-(float)d * (9.210340371976184f / 128.0f)); // 10000^(-d/128)
    float ang = (float)t * inv;
    float sn, cs;
    sincosf(ang, &sn, &cs);
    size_t base = ro + (size_t)h * 256 + d;
    float q1 = (float)q[base], q2 = (float)q[base + 128];
    q[base]       = (__bf16)(q1 * cs - q2 * sn);
    q[base + 128] = (__bf16)(q2 * cs + q1 * sn);
    float dec = expf(sgc[(size_t)(b * 4 + h) * T + t]);
    float k1 = (float)k[base], k2 = (float)k[base + 128];
    k[base]       = (__bf16)((k1 * cs - k2 * sn) * dec);
    k[base + 128] = (__bf16)((k2 * cs + k1 * sn) * dec);
  }
  #pragma unroll
  for (int i = 0; i < 4; i++) {
    int e = tid + 256 * i;
    float v = (float)s[ro + e];
    v = fminf(fmaxf(v, -32.f), 32.f);
    s[ro + e] = (__bf16)expf(v);
  }
}

// ---------------------------------------------------------------------------
// per-chunk states:
//   HKc[bh][c][m][k] = sum_t A[t][m] K[t][k]   (part 0/1: m-halves)
//   HVc[bh][c][v][m] = sum_t V[t][v] A[t][m]   (part 2/3: v-halves)
//   csA[bh][c][m]    = sum_t A[t][m]           (part 2)
// ---------------------------------------------------------------------------
__global__ __launch_bounds__(256)
void chunkstate_kernel(const __bf16* __restrict__ kg, const __bf16* __restrict__ vg,
                       const __bf16* __restrict__ ag,
                       __bf16* __restrict__ HKc, __bf16* __restrict__ HVc,
                       float* __restrict__ csA)
{
  using namespace abc;
  const int c = blockIdx.x, bh = blockIdx.y, part = blockIdx.z;
  const int b = bh >> 2, h = bh & 3;
  const size_t R = (size_t)b * T + (size_t)c * CH;
  const int F = h * 256;
  const bool isHV = part >= 2;
  const int p2 = part & 1;
  const __bf16* Xsrc = isHV ? vg : ag;   // A-operand source (transposed)
  const __bf16* Ysrc = isHV ? ag : kg;   // B-operand source (transposed)
  __shared__ __bf16 Xt[256][72];
  __shared__ __bf16 Yt[256][72];
  const int tid = threadIdx.x;
  #pragma unroll
  for (int j = 0; j < 8; j++) {
    int p = tid + 256 * j;               // 2048 vec8 chunks over 64x256
    int i = p >> 5, fq = p & 31;
    bf8_t xv = *reinterpret_cast<const bf8_t*>(Xsrc + (R + i) * 1024 + F + fq * 8);
    bf8_t yv = *reinterpret_cast<const bf8_t*>(Ysrc + (R + i) * 1024 + F + fq * 8);
    #pragma unroll
    for (int u = 0; u < 8; u++) { Xt[fq * 8 + u][i] = xv[u]; Yt[fq * 8 + u][i] = yv[u]; }
  }
  __syncthreads();
  if (part == 2) {
    float ssum = 0.f;
    #pragma unroll 8
    for (int t = 0; t < CH; t++) ssum += (float)Yt[tid][t];
    csA[((size_t)bh * NC + c) * 256 + tid] = ssum;
  }
  const int lane = tid & 63, wvid = tid >> 6;
  const int quad = lane >> 4, l16 = lane & 15;
  const int row0 = p2 * 128 + wvid * 32;
  const f4_t fzero = {0.f, 0.f, 0.f, 0.f};
  f4_t acc[2][16];
  #pragma unroll
  for (int a = 0; a < 2; a++)
    #pragma unroll
    for (int ct = 0; ct < 16; ct++) acc[a][ct] = fzero;
  #pragma unroll
  for (int ks = 0; ks < 2; ks++) {
    bf8_t af0 = *reinterpret_cast<const bf8_t*>(&Xt[row0 + l16][ks * 32 + quad * 8]);
    bf8_t af1 = *reinterpret_cast<const bf8_t*>(&Xt[row0 + 16 + l16][ks * 32 + quad * 8]);
    #pragma unroll
    for (int ct = 0; ct < 16; ct++) {
      bf8_t bv = *reinterpret_cast<const bf8_t*>(&Yt[ct * 16 + l16][ks * 32 + quad * 8]);
      acc[0][ct] = mfma16(af0, bv, acc[0][ct]);
      acc[1][ct] = mfma16(af1, bv, acc[1][ct]);
    }
  }
  __bf16* out = (isHV ? HVc : HKc) + ((size_t)bh * NC + c) * 65536;
  #pragma unroll
  for (int rt = 0; rt < 2; rt++)
    #pragma unroll
    for (int ct = 0; ct < 16; ct++)
      #pragma unroll
      for (int r = 0; r < 4; r++)
        out[(size_t)(row0 + rt * 16 + quad * 4 + r) * 256 + ct * 16 + l16] =
            (__bf16)acc[rt][ct][r];
}

// ---------------------------------------------------------------------------
// in-place exclusive prefix over chunk axis of HKc/HVc (bf16, fp32 run)
// ---------------------------------------------------------------------------
__global__ __launch_bounds__(256)
void prefix_state_kernel(__bf16* __restrict__ HKc, __bf16* __restrict__ HVc)
{
  using namespace abc;
  const int bh = blockIdx.y;
  __bf16* base = (blockIdx.z ? HVc : HKc) + (size_t)bh * NC * 65536;
  const int e = (blockIdx.x * 256 + threadIdx.x) * 4;
  float run0 = 0, run1 = 0, run2 = 0, run3 = 0;
  for (int c = 0; c < NC; c++) {
    __bf16* p = base + (size_t)c * 65536 + e;
    bf4_t v = *reinterpret_cast<const bf4_t*>(p);
    bf4_t o;
    o[0] = (__bf16)run0; o[1] = (__bf16)run1; o[2] = (__bf16)run2; o[3] = (__bf16)run3;
    run0 += (float)v[0]; run1 += (float)v[1]; run2 += (float)v[2]; run3 += (float)v[3];
    *reinterpret_cast<bf4_t*>(p) = o;
  }
}

__global__ __launch_bounds__(256)
void prefix_csa_kernel(float* __restrict__ csA)
{
  using namespace abc;
  const int bh = blockIdx.x, m = threadIdx.x;
  float run = 0.f;
  for (int c = 0; c < NC; c++) {
    float* p = csA + ((size_t)bh * NC + c) * 256 + m;
    float v = *p; *p = run; run += v;
  }
}

// ---------------------------------------------------------------------------
// main chunked ABC attention + fused RMSNorm/SiLU-gate epilogue
// one block per (chunk, bh): 256 threads, 4 waves, each wave a 16-row strip
// ---------------------------------------------------------------------------
__global__ __launch_bounds__(256)
void attn_kernel(const __bf16* __restrict__ qg, const __bf16* __restrict__ kg,
                 const __bf16* __restrict__ vg, const __bf16* __restrict__ ag,
                 const __bf16* __restrict__ gg,
                 const __bf16* __restrict__ HKp, const __bf16* __restrict__ HVp,
                 const float* __restrict__ Zp, const float* __restrict__ gnw,
                 __bf16* __restrict__ yout)
{
  using namespace abc;
  const int c = blockIdx.x, bh = blockIdx.y;
  const int b = bh >> 2, h = bh & 3;
  const size_t R = (size_t)b * T + (size_t)c * CH;
  const int F = h * 256;
  const int tid = threadIdx.x;
  const int lane = tid & 63, wvid = tid >> 6;
  const int quad = lane >> 4, l16 = lane & 15;

  __shared__ __bf16 As[64][264];   // A chunk, natural [t][m]
  __shared__ __bf16 Vs[64][264];   // V chunk, natural [t][v]
  __shared__ __bf16 Ls[64][72];    // lower-triangular ones
  __shared__ __bf16 S1s[64][72];   // masked QK^T, later masked P
  __shared__ __bf16 Ws[64][264];   // W = qv / SumA
  __shared__ float zs[256];
  __shared__ float gns[256];

  #pragma unroll
  for (int j = 0; j < 8; j++) {
    int p = tid + 256 * j;
    int i = p >> 5, mq = p & 31;
    *reinterpret_cast<bf8_t*>(&As[i][mq * 8]) =
        *reinterpret_cast<const bf8_t*>(ag + (R + i) * 1024 + F + mq * 8);
    *reinterpret_cast<bf8_t*>(&Vs[i][mq * 8]) =
        *reinterpret_cast<const bf8_t*>(vg + (R + i) * 1024 + F + mq * 8);
  }
  for (int j = 0; j < 18; j++) {
    int p = tid + 256 * j;
    if (p < 64 * 72) {
      int t = p / 72, i = p % 72;
      Ls[t][i] = (i <= t) ? (__bf16)1.0f : (__bf16)0.0f;
    }
  }
  zs[tid] = Zp[((size_t)bh * NC + c) * 256 + tid];
  gns[tid] = gnw[tid];
  __syncthreads();

  const f4_t fzero = {0.f, 0.f, 0.f, 0.f};
  const __bf16* qrow = qg + (R + wvid * 16 + l16) * 1024 + F;

  // phase A: S1 = Q K^T  (intra-chunk), A/B frags straight from global
  f4_t s1a[4];
  #pragma unroll
  for (int it = 0; it < 4; it++) s1a[it] = fzero;
  #pragma unroll
  for (int ks = 0; ks < 8; ks++) {
    bf8_t aq = *reinterpret_cast<const bf8_t*>(qrow + ks * 32 + quad * 8);
    #pragma unroll
    for (int it = 0; it < 4; it++) {
      bf8_t bk = *reinterpret_cast<const bf8_t*>(
          kg + (R + it * 16 + l16) * 1024 + F + ks * 32 + quad * 8);
      s1a[it] = mfma16(aq, bk, s1a[it]);
    }
  }
  #pragma unroll
  for (int it = 0; it < 4; it++)
    #pragma unroll
    for (int r = 0; r < 4; r++) {
      int tl = wvid * 16 + quad * 4 + r;
      int il = it * 16 + l16;
      S1s[tl][il] = (il <= tl) ? (__bf16)s1a[it][r] : (__bf16)0.0f;
    }
  __syncthreads();

  // phase B: intra numerator (S1_masked @ A) and cumA (L @ A)
  f4_t aok[16], acum[16];
  #pragma unroll
  for (int mt = 0; mt < 16; mt++) { aok[mt] = fzero; acum[mt] = fzero; }
  #pragma unroll
  for (int iks = 0; iks < 2; iks++) {
    bf8_t s1f = *reinterpret_cast<const bf8_t*>(&S1s[wvid * 16 + l16][iks * 32 + quad * 8]);
    bf8_t lf  = *reinterpret_cast<const bf8_t*>(&Ls [wvid * 16 + l16][iks * 32 + quad * 8]);
    #pragma unroll
    for (int mt = 0; mt < 16; mt++) {
      bf8_t bfa;
      #pragma unroll
      for (int w = 0; w < 8; w++) {        // quad-swizzled transposed reads
        int j = (w + 2 * quad) & 7;
        bfa[j] = As[iks * 32 + quad * 8 + j][mt * 16 + l16];
      }
      aok[mt]  = mfma16(s1f, bfa, aok[mt]);
      acum[mt] = mfma16(lf,  bfa, acum[mt]);
    }
  }
  // phase C: cross numerator  Q @ HKpre ([m][k] layout, frags from global)
  const __bf16* hkb = HKp + ((size_t)bh * NC + c) * 65536;
  #pragma unroll
  for (int ks = 0; ks < 8; ks++) {
    bf8_t aq = *reinterpret_cast<const bf8_t*>(qrow + ks * 32 + quad * 8);
    #pragma unroll
    for (int mt = 0; mt < 16; mt++) {
      bf8_t bv = *reinterpret_cast<const bf8_t*>(
          hkb + (size_t)(mt * 16 + l16) * 256 + ks * 32 + quad * 8);
      aok[mt] = mfma16(aq, bv, aok[mt]);
    }
  }
  // softmax over m (in-register, 16-lane quad groups) ; W = qv / SumA
  #pragma unroll
  for (int r = 0; r < 4; r++) {
    float ovv[16], sa[16];
    float mx = -3.0e38f;
    #pragma unroll
    for (int mt = 0; mt < 16; mt++) {
      sa[mt] = zs[mt * 16 + l16] + acum[mt][r];
      ovv[mt] = SCALE * aok[mt][r] / sa[mt];
      mx = fmaxf(mx, ovv[mt]);
    }
    #pragma unroll
    for (int off = 1; off < 16; off <<= 1) mx = fmaxf(mx, __shfl_xor(mx, off));
    float se = 0.f;
    #pragma unroll
    for (int mt = 0; mt < 16; mt++) { ovv[mt] = __expf(ovv[mt] - mx); se += ovv[mt]; }
    #pragma unroll
    for (int off = 1; off < 16; off <<= 1) se += __shfl_xor(se, off);
    float inv = 1.0f / se;
    int tl = wvid * 16 + quad * 4 + r;
    #pragma unroll
    for (int mt = 0; mt < 16; mt++)
      Ws[tl][mt * 16 + l16] = (__bf16)(ovv[mt] * inv / sa[mt]);
  }
  __syncthreads();

  // phase 4a: P = mask(W @ A^T)   (contraction over m; As natural is B-op)
  f4_t pacc[4];
  #pragma unroll
  for (int it = 0; it < 4; it++) pacc[it] = fzero;
  #pragma unroll
  for (int ks = 0; ks < 8; ks++) {
    bf8_t wf = *reinterpret_cast<const bf8_t*>(&Ws[wvid * 16 + l16][ks * 32 + quad * 8]);
    #pragma unroll
    for (int it = 0; it < 4; it++) {
      bf8_t ba = *reinterpret_cast<const bf8_t*>(&As[it * 16 + l16][ks * 32 + quad * 8]);
      pacc[it] = mfma16(wf, ba, pacc[it]);
    }
  }
  #pragma unroll
  for (int it = 0; it < 4; it++)
    #pragma unroll
    for (int r = 0; r < 4; r++) {
      int tl = wvid * 16 + quad * 4 + r;
      int il = it * 16 + l16;
      S1s[tl][il] = (il <= tl) ? (__bf16)pacc[it][r] : (__bf16)0.0f;
    }
  __syncthreads();

  // phase 4b: O = W @ HVpre^T + P @ V
  f4_t oacc[16];
  #pragma unroll
  for (int vt = 0; vt < 16; vt++) oacc[vt] = fzero;
  const __bf16* hvb = HVp + ((size_t)bh * NC + c) * 65536;
  #pragma unroll
  for (int ks = 0; ks < 8; ks++) {
    bf8_t wf = *reinterpret_cast<const bf8_t*>(&Ws[wvid * 16 + l16][ks * 32 + quad * 8]);
    #pragma unroll
    for (int vt = 0; vt < 16; vt++) {
      bf8_t bv = *reinterpret_cast<const bf8_t*>(
          hvb + (size_t)(vt * 16 + l16) * 256 + ks * 32 + quad * 8);
      oacc[vt] = mfma16(wf, bv, oacc[vt]);
    }
  }
  #pragma unroll
  for (int iks = 0; iks < 2; iks++) {
    bf8_t pf = *reinterpret_cast<const bf8_t*>(&S1s[wvid * 16 + l16][iks * 32 + quad * 8]);
    #pragma unroll
    for (int vt = 0; vt < 16; vt++) {
      bf8_t bvt;
      #pragma unroll
      for (int w = 0; w < 8; w++) {
        int j = (w + 2 * quad) & 7;
        bvt[j] = Vs[iks * 32 + quad * 8 + j][vt * 16 + l16];
      }
      oacc[vt] = mfma16(pf, bvt, oacc[vt]);
    }
  }
  // epilogue: fused RMSNorm * gn_w * g * sigmoid(g) -> y (bf16)
  #pragma unroll
  for (int r = 0; r < 4; r++) {
    float ss = 0.f;
    #pragma unroll
    for (int vt = 0; vt < 16; vt++) ss += oacc[vt][r] * oacc[vt][r];
    #pragma unroll
    for (int off = 1; off < 16; off <<= 1) ss += __shfl_xor(ss, off);
    float rinv = rsqrtf(ss * (1.0f / 256.0f) + EPS);
    int tl = wvid * 16 + quad * 4 + r;
    const __bf16* grow = gg + (R + tl) * 1024 + F;
    __bf16* yrow = yout + (R + tl) * 1024 + F;
    #pragma unroll
    for (int vt = 0; vt < 16; vt++) {
      int v = vt * 16 + l16;
      float gvl = (float)grow[v];
      float yv = oacc[vt][r] * rinv * gns[v] * gvl / (1.0f + __expf(-gvl));
      yrow[v] = (__bf16)yv;
    }
  }
}

// ---------------------------------------------------------------------------
extern "C" void kernel_launch(void* const* d_in, const int* in_sizes, int n_in,
                              void* d_out, int out_size, void* d_ws, size_t ws_size,
                              hipStream_t stream) {
  using namespace abc;
  (void)in_sizes; (void)n_in; (void)out_size; (void)ws_size;
  const float* x    = (const float*)d_in[0];
  const float* q_w  = (const float*)d_in[1];
  const float* k_w  = (const float*)d_in[2];
  const float* v_w  = (const float*)d_in[3];
  const float* g_w  = (const float*)d_in[4];
  const float* s_w  = (const float*)d_in[5];
  const float* sg_w = (const float*)d_in[6];
  const float* gn_w = (const float*)d_in[7];
  const float* o_w  = (const float*)d_in[8];
  float* out = (float*)d_out;

  char* ws = (char*)d_ws;
  const size_t PROJ = (size_t)BT * 1024;       // elements per projection
  __bf16* proj = (__bf16*)ws;                  // q,k,v,g,a,y : 6 x 16MB
  __bf16* q_bf = proj + 0 * PROJ;
  __bf16* k_bf = proj + 1 * PROJ;
  __bf16* v_bf = proj + 2 * PROJ;
  __bf16* g_bf = proj + 3 * PROJ;
  __bf16* a_bf = proj + 4 * PROJ;
  __bf16* y_bf = proj + 5 * PROJ;
  float* sgl = (float*)(ws + (size_t)96 * 1024 * 1024);
  float* sgc = sgl + (size_t)BH * T;
  float* csA = sgc + (size_t)BH * T;           // 16*32*256 floats
  __bf16* HKc = (__bf16*)(ws + (size_t)97 * 1024 * 1024);   // 64MB
  __bf16* HVc = HKc + (size_t)BH * NC * 65536;               // 64MB

  dim3 blk(256);
  gemm_kernel<false, true><<<dim3(8, 64, 5), blk, 0, stream>>>(
      x, q_w, k_w, v_w, g_w, s_w, proj, 1024);
  sg_kernel<<<dim3(BT / 4), blk, 0, stream>>>(x, sg_w, sgl);
  scan_kernel<<<dim3(BH), blk, 0, stream>>>(sgl, sgc);
  prep_kernel<<<dim3(BT), blk, 0, stream>>>(q_bf, k_bf, a_bf, sgc);
  chunkstate_kernel<<<dim3(NC, BH, 4), blk, 0, stream>>>(
      k_bf, v_bf, a_bf, HKc, HVc, csA);
  prefix_state_kernel<<<dim3(64, BH, 2), blk, 0, stream>>>(HKc, HVc);
  prefix_csa_kernel<<<dim3(BH), blk, 0, stream>>>(csA);
  attn_kernel<<<dim3(NC, BH), blk, 0, stream>>>(
      q_bf, k_bf, v_bf, a_bf, g_bf, HKc, HVc, csA, gn_w, y_bf);
  gemm_kernel<true, false><<<dim3(8, 64, 1), blk, 0, stream>>>(
      y_bf, o_w, o_w, o_w, o_w, o_w, out, 1024);
}

// Round 2
// 655.865 us; speedup vs baseline: 1.4356x; 1.4356x over previous
//
#include <hip/hip_runtime.h>
#include <hip/hip_bf16.h>
#include <stdint.h>
#include <stddef.h>
#include <math.h>

typedef __bf16 bf8_t __attribute__((ext_vector_type(8)));
typedef __bf16 bf4_t __attribute__((ext_vector_type(4)));
typedef float  f4_t  __attribute__((ext_vector_type(4)));
typedef unsigned int u32;

#define DEV static __device__ __forceinline__

namespace abc {
constexpr int B = 4, T = 2048, D = 1024, H = 4;
constexpr int BT = B * T;          // 8192
constexpr int CH = 64;             // chunk length
constexpr int NC = T / CH;         // 32 chunks
constexpr int BH = B * H;          // 16
constexpr float SCALE = 0.0625f;   // DK^-0.5
constexpr float GN = 16.0f;
constexpr float EPS = 1e-5f;
}

DEV f4_t mfma16(bf8_t a, bf8_t b, f4_t c) {
  return __builtin_amdgcn_mfma_f32_16x16x32_bf16(a, b, c, 0, 0, 0);
}

// async global->LDS, 16B per lane; lds dest must be wave-uniform base (+lane*16)
DEV void glds16(const void* g, void* l) {
  __builtin_amdgcn_global_load_lds(
      (const __attribute__((address_space(1))) u32*)g,
      (__attribute__((address_space(3))) u32*)l, 16, 0, 0);
}

// ---------------------------------------------------------------------------
// x fp32 -> bf16 (row-major unchanged). 8 elems/thread.
// ---------------------------------------------------------------------------
__global__ __launch_bounds__(256)
void cvt_x_kernel(const float* __restrict__ x, __bf16* __restrict__ xb)
{
  const int idx = blockIdx.x * 256 + threadIdx.x;   // 1M threads total
  const float4* src = reinterpret_cast<const float4*>(x);
  float4 a = src[(size_t)idx * 2];
  float4 b = src[(size_t)idx * 2 + 1];
  bf8_t o;
  o[0] = (__bf16)a.x; o[1] = (__bf16)a.y; o[2] = (__bf16)a.z; o[3] = (__bf16)a.w;
  o[4] = (__bf16)b.x; o[5] = (__bf16)b.y; o[6] = (__bf16)b.z; o[7] = (__bf16)b.w;
  reinterpret_cast<bf8_t*>(xb)[idx] = o;
}

// ---------------------------------------------------------------------------
// weight fp32 [k][n] -> bf16 [n][k] (transpose), 64x64 tiles, 6 weights
// ---------------------------------------------------------------------------
__global__ __launch_bounds__(256)
void cvt_w_kernel(const float* __restrict__ w0, const float* __restrict__ w1,
                  const float* __restrict__ w2, const float* __restrict__ w3,
                  const float* __restrict__ w4, const float* __restrict__ w5,
                  __bf16* __restrict__ wt)
{
  const int z = blockIdx.z;
  const float* W = (z == 0) ? w0 : (z == 1) ? w1 : (z == 2) ? w2
                 : (z == 3) ? w3 : (z == 4) ? w4 : w5;
  const int n0 = blockIdx.x * 64, k0 = blockIdx.y * 64;
  __shared__ __bf16 Ts[64][72];
  const int tid = threadIdx.x;
  #pragma unroll
  for (int i = 0; i < 4; i++) {
    int p = tid + 256 * i;            // 1024 float4 chunks: 64 k-rows x 16
    int row = p >> 4, c4 = p & 15;
    float4 v = *reinterpret_cast<const float4*>(W + (size_t)(k0 + row) * 1024 + n0 + c4 * 4);
    Ts[c4 * 4 + 0][row] = (__bf16)v.x;
    Ts[c4 * 4 + 1][row] = (__bf16)v.y;
    Ts[c4 * 4 + 2][row] = (__bf16)v.z;
    Ts[c4 * 4 + 3][row] = (__bf16)v.w;
  }
  __syncthreads();
  #pragma unroll
  for (int i = 0; i < 2; i++) {
    int p = tid + 256 * i;            // 512 bf8 chunks: 64 n-rows x 8
    int n = p >> 3, kq = p & 7;
    bf8_t o = *reinterpret_cast<const bf8_t*>(&Ts[n][kq * 8]);
    *reinterpret_cast<bf8_t*>(wt + (size_t)z * 1024 * 1024 + (size_t)(n0 + n) * 1024 + k0 + kq * 8) = o;
  }
}

// ---------------------------------------------------------------------------
// m97-style GEMM: C[8192 x 1024] = A[8192 x 1024] * Bt[z][n][k]^T
// 128x128 tile, BK=64, global_load_lds width-16 staging, unpadded LDS.
// ---------------------------------------------------------------------------
template<bool OUT_BF16>
__global__ __launch_bounds__(256)
void gemm_bt_kernel(const __bf16* __restrict__ A, const __bf16* __restrict__ BtB,
                    void* __restrict__ Cp)
{
  using namespace abc;
  constexpr int K = 1024;
  const int z = blockIdx.z;
  const __bf16* Bt = BtB + (size_t)z * K * 1024;
  const int n0 = blockIdx.x * 128;
  const int m0 = blockIdx.y * 128;
  __shared__ __bf16 As[128 * 64];   // [m][k], unpadded (global_load_lds layout)
  __shared__ __bf16 Bs[128 * 64];   // [n][k]
  const int tid = threadIdx.x;
  const int lane = tid & 63, wvid = tid >> 6;
  const int wr = wvid >> 1, wc = wvid & 1;
  const int quad = lane >> 4, l16 = lane & 15;
  const f4_t fzero = {0.f, 0.f, 0.f, 0.f};
  f4_t acc[4][4];
  #pragma unroll
  for (int i = 0; i < 4; i++)
    #pragma unroll
    for (int j = 0; j < 4; j++) acc[i][j] = fzero;

  const int chunk_row = tid >> 3;          // 0..31 within each i-group of 32 rows
  const int chunk_col = tid & 7;           // 8 x 16B per 128B row
  for (int k0 = 0; k0 < K; k0 += 64) {
    __syncthreads();
    #pragma unroll
    for (int i = 0; i < 4; i++) {
      glds16(A + (size_t)(m0 + i * 32 + chunk_row) * K + k0 + chunk_col * 8,
             &As[(size_t)(i * 256 + wvid * 64) * 8]);
    }
    #pragma unroll
    for (int i = 0; i < 4; i++) {
      glds16(Bt + (size_t)(n0 + i * 32 + chunk_row) * K + k0 + chunk_col * 8,
             &Bs[(size_t)(i * 256 + wvid * 64) * 8]);
    }
    __syncthreads();
    #pragma unroll
    for (int ks = 0; ks < 2; ks++) {
      bf8_t af[4], bfv[4];
      #pragma unroll
      for (int i = 0; i < 4; i++)
        af[i] = *reinterpret_cast<const bf8_t*>(
            &As[(size_t)(wr * 64 + i * 16 + l16) * 64 + ks * 32 + quad * 8]);
      #pragma unroll
      for (int j = 0; j < 4; j++)
        bfv[j] = *reinterpret_cast<const bf8_t*>(
            &Bs[(size_t)(wc * 64 + j * 16 + l16) * 64 + ks * 32 + quad * 8]);
      #pragma unroll
      for (int i = 0; i < 4; i++)
        #pragma unroll
        for (int j = 0; j < 4; j++)
          acc[i][j] = mfma16(af[i], bfv[j], acc[i][j]);
    }
  }
  const int crow = m0 + wr * 64, ccol = n0 + wc * 64;
  if (OUT_BF16) {
    __bf16* C = (__bf16*)Cp + (size_t)z * BT * 1024;
    #pragma unroll
    for (int i = 0; i < 4; i++)
      #pragma unroll
      for (int j = 0; j < 4; j++)
        #pragma unroll
        for (int r = 0; r < 4; r++)
          C[(size_t)(crow + i * 16 + quad * 4 + r) * 1024 + ccol + j * 16 + l16] =
              (__bf16)acc[i][j][r];
  } else {
    float* C = (float*)Cp;
    #pragma unroll
    for (int i = 0; i < 4; i++)
      #pragma unroll
      for (int j = 0; j < 4; j++)
        #pragma unroll
        for (int r = 0; r < 4; r++)
          C[(size_t)(crow + i * 16 + quad * 4 + r) * 1024 + ccol + j * 16 + l16] =
              acc[i][j][r];
  }
}

// ---------------------------------------------------------------------------
// sg projection: sgl[bh][t] = log_sigmoid(x[b,t,:] . sg_w[:,h]) / 16
// ---------------------------------------------------------------------------
__global__ __launch_bounds__(256)
void sg_kernel(const float* __restrict__ x, const float* __restrict__ sgw,
               float* __restrict__ sgl)
{
  using namespace abc;
  const int wvid = threadIdx.x >> 6, lane = threadIdx.x & 63;
  const int bt = blockIdx.x * 4 + wvid;
  const float* xr = x + (size_t)bt * 1024;
  float a0 = 0, a1 = 0, a2 = 0, a3 = 0;
  #pragma unroll 4
  for (int u = 0; u < 16; u++) {
    int i = u * 64 + lane;
    float xv = xr[i];
    float4 w = *reinterpret_cast<const float4*>(sgw + (size_t)i * 4);
    a0 += xv * w.x; a1 += xv * w.y; a2 += xv * w.z; a3 += xv * w.w;
  }
  #pragma unroll
  for (int off = 32; off > 0; off >>= 1) {
    a0 += __shfl_down(a0, off);
    a1 += __shfl_down(a1, off);
    a2 += __shfl_down(a2, off);
    a3 += __shfl_down(a3, off);
  }
  if (lane == 0) {
    const int b = bt >> 11, t = bt & (T - 1);
    float r[4] = {a0, a1, a2, a3};
    #pragma unroll
    for (int h = 0; h < 4; h++) {
      float v = r[h];
      float ls = fminf(v, 0.f) - log1pf(expf(-fabsf(v)));
      sgl[(size_t)(b * 4 + h) * T + t] = ls * (1.0f / GN);
    }
  }
}

// ---------------------------------------------------------------------------
// inclusive cumsum over T per (b,h)
// ---------------------------------------------------------------------------
__global__ __launch_bounds__(256)
void scan_kernel(const float* __restrict__ sgl, float* __restrict__ sgc)
{
  using namespace abc;
  const int bh = blockIdx.x;
  const float* in = sgl + (size_t)bh * T;
  float* out = sgc + (size_t)bh * T;
  __shared__ float part[256];
  const int tid = threadIdx.x;
  float v[8]; float s = 0.f;
  #pragma unroll
  for (int i = 0; i < 8; i++) { v[i] = in[tid * 8 + i]; s += v[i]; }
  part[tid] = s;
  __syncthreads();
  for (int off = 1; off < 256; off <<= 1) {
    float a = (tid >= off) ? part[tid - off] : 0.f;
    __syncthreads();
    part[tid] += a;
    __syncthreads();
  }
  float run = (tid > 0) ? part[tid - 1] : 0.f;
  #pragma unroll
  for (int i = 0; i < 8; i++) { run += v[i]; out[tid * 8 + i] = run; }
}

// ---------------------------------------------------------------------------
// prep: RoPE(q), RoPE(k)*exp(cumsum sg), s -> exp(clamp(s)) ; in-place on bf16
// ---------------------------------------------------------------------------
__global__ __launch_bounds__(256)
void prep_kernel(__bf16* __restrict__ q, __bf16* __restrict__ k,
                 __bf16* __restrict__ s, const float* __restrict__ sgc)
{
  using namespace abc;
  const int bt = blockIdx.x;
  const int b = bt >> 11, t = bt & (T - 1);
  const int tid = threadIdx.x;
  const size_t ro = (size_t)bt * 1024;
  #pragma unroll
  for (int i = 0; i < 2; i++) {
    int p = tid + 256 * i;          // 0..511 : h = p/128, d = p%128
    int h = p >> 7, d = p & 127;
    float inv = expf(-(float)d * (9.210340371976184f / 128.0f)); // 10000^(-d/128)
    float ang = (float)t * inv;
    float sn, cs;
    sincosf(ang, &sn, &cs);
    size_t base = ro + (size_t)h * 256 + d;
    float q1 = (float)q[base], q2 = (float)q[base + 128];
    q[base]       = (__bf16)(q1 * cs - q2 * sn);
    q[base + 128] = (__bf16)(q2 * cs + q1 * sn);
    float dec = expf(sgc[(size_t)(b * 4 + h) * T + t]);
    float k1 = (float)k[base], k2 = (float)k[base + 128];
    k[base]       = (__bf16)((k1 * cs - k2 * sn) * dec);
    k[base + 128] = (__bf16)((k2 * cs + k1 * sn) * dec);
  }
  #pragma unroll
  for (int i = 0; i < 4; i++) {
    int e = tid + 256 * i;
    float v = (float)s[ro + e];
    v = fminf(fmaxf(v, -32.f), 32.f);
    s[ro + e] = (__bf16)expf(v);
  }
}

// ---------------------------------------------------------------------------
// per-chunk states:
//   HKc[bh][c][m][k] = sum_t A[t][m] K[t][k]   (part 0/1: m-halves)
//   HVc[bh][c][v][m] = sum_t V[t][v] A[t][m]   (part 2/3: v-halves)
//   csA[bh][c][m]    = sum_t A[t][m]           (part 2)
// ---------------------------------------------------------------------------
__global__ __launch_bounds__(256)
void chunkstate_kernel(const __bf16* __restrict__ kg, const __bf16* __restrict__ vg,
                       const __bf16* __restrict__ ag,
                       __bf16* __restrict__ HKc, __bf16* __restrict__ HVc,
                       float* __restrict__ csA)
{
  using namespace abc;
  const int c = blockIdx.x, bh = blockIdx.y, part = blockIdx.z;
  const int b = bh >> 2, h = bh & 3;
  const size_t R = (size_t)b * T + (size_t)c * CH;
  const int F = h * 256;
  const bool isHV = part >= 2;
  const int p2 = part & 1;
  const __bf16* Xsrc = isHV ? vg : ag;   // A-operand source (transposed)
  const __bf16* Ysrc = isHV ? ag : kg;   // B-operand source (transposed)
  __shared__ __bf16 Xt[256][72];
  __shared__ __bf16 Yt[256][72];
  const int tid = threadIdx.x;
  #pragma unroll
  for (int j = 0; j < 8; j++) {
    int p = tid + 256 * j;               // 2048 vec8 chunks over 64x256
    int i = p >> 5, fq = p & 31;
    bf8_t xv = *reinterpret_cast<const bf8_t*>(Xsrc + (R + i) * 1024 + F + fq * 8);
    bf8_t yv = *reinterpret_cast<const bf8_t*>(Ysrc + (R + i) * 1024 + F + fq * 8);
    #pragma unroll
    for (int u = 0; u < 8; u++) { Xt[fq * 8 + u][i] = xv[u]; Yt[fq * 8 + u][i] = yv[u]; }
  }
  __syncthreads();
  if (part == 2) {
    float ssum = 0.f;
    #pragma unroll 8
    for (int t = 0; t < CH; t++) ssum += (float)Yt[tid][t];
    csA[((size_t)bh * NC + c) * 256 + tid] = ssum;
  }
  const int lane = tid & 63, wvid = tid >> 6;
  const int quad = lane >> 4, l16 = lane & 15;
  const int row0 = p2 * 128 + wvid * 32;
  const f4_t fzero = {0.f, 0.f, 0.f, 0.f};
  f4_t acc[2][16];
  #pragma unroll
  for (int a = 0; a < 2; a++)
    #pragma unroll
    for (int ct = 0; ct < 16; ct++) acc[a][ct] = fzero;
  #pragma unroll
  for (int ks = 0; ks < 2; ks++) {
    bf8_t af0 = *reinterpret_cast<const bf8_t*>(&Xt[row0 + l16][ks * 32 + quad * 8]);
    bf8_t af1 = *reinterpret_cast<const bf8_t*>(&Xt[row0 + 16 + l16][ks * 32 + quad * 8]);
    #pragma unroll
    for (int ct = 0; ct < 16; ct++) {
      bf8_t bv = *reinterpret_cast<const bf8_t*>(&Yt[ct * 16 + l16][ks * 32 + quad * 8]);
      acc[0][ct] = mfma16(af0, bv, acc[0][ct]);
      acc[1][ct] = mfma16(af1, bv, acc[1][ct]);
    }
  }
  __bf16* out = (isHV ? HVc : HKc) + ((size_t)bh * NC + c) * 65536;
  #pragma unroll
  for (int rt = 0; rt < 2; rt++)
    #pragma unroll
    for (int ct = 0; ct < 16; ct++)
      #pragma unroll
      for (int r = 0; r < 4; r++)
        out[(size_t)(row0 + rt * 16 + quad * 4 + r) * 256 + ct * 16 + l16] =
            (__bf16)acc[rt][ct][r];
}

// ---------------------------------------------------------------------------
// in-place exclusive prefix over chunk axis of HKc/HVc (bf16, fp32 run)
// ---------------------------------------------------------------------------
__global__ __launch_bounds__(256)
void prefix_state_kernel(__bf16* __restrict__ HKc, __bf16* __restrict__ HVc)
{
  using namespace abc;
  const int bh = blockIdx.y;
  __bf16* base = (blockIdx.z ? HVc : HKc) + (size_t)bh * NC * 65536;
  const int e = (blockIdx.x * 256 + threadIdx.x) * 4;
  float run0 = 0, run1 = 0, run2 = 0, run3 = 0;
  for (int c = 0; c < NC; c++) {
    __bf16* p = base + (size_t)c * 65536 + e;
    bf4_t v = *reinterpret_cast<const bf4_t*>(p);
    bf4_t o;
    o[0] = (__bf16)run0; o[1] = (__bf16)run1; o[2] = (__bf16)run2; o[3] = (__bf16)run3;
    run0 += (float)v[0]; run1 += (float)v[1]; run2 += (float)v[2]; run3 += (float)v[3];
    *reinterpret_cast<bf4_t*>(p) = o;
  }
}

__global__ __launch_bounds__(256)
void prefix_csa_kernel(float* __restrict__ csA)
{
  using namespace abc;
  const int bh = blockIdx.x, m = threadIdx.x;
  float run = 0.f;
  for (int c = 0; c < NC; c++) {
    float* p = csA + ((size_t)bh * NC + c) * 256 + m;
    float v = *p; *p = run; run += v;
  }
}

// ---------------------------------------------------------------------------
// main chunked ABC attention + fused RMSNorm/SiLU-gate epilogue
// ---------------------------------------------------------------------------
__global__ __launch_bounds__(256)
void attn_kernel(const __bf16* __restrict__ qg, const __bf16* __restrict__ kg,
                 const __bf16* __restrict__ vg, const __bf16* __restrict__ ag,
                 const __bf16* __restrict__ gg,
                 const __bf16* __restrict__ HKp, const __bf16* __restrict__ HVp,
                 const float* __restrict__ Zp, const float* __restrict__ gnw,
                 __bf16* __restrict__ yout)
{
  using namespace abc;
  const int c = blockIdx.x, bh = blockIdx.y;
  const int b = bh >> 2, h = bh & 3;
  const size_t R = (size_t)b * T + (size_t)c * CH;
  const int F = h * 256;
  const int tid = threadIdx.x;
  const int lane = tid & 63, wvid = tid >> 6;
  const int quad = lane >> 4, l16 = lane & 15;

  __shared__ __bf16 As[64][264];   // A chunk, natural [t][m]
  __shared__ __bf16 Vs[64][264];   // V chunk, natural [t][v]
  __shared__ __bf16 Ls[64][72];    // lower-triangular ones
  __shared__ __bf16 S1s[64][72];   // masked QK^T, later masked P
  __shared__ __bf16 Ws[64][264];   // W = qv / SumA
  __shared__ float zs[256];
  __shared__ float gns[256];

  #pragma unroll
  for (int j = 0; j < 8; j++) {
    int p = tid + 256 * j;
    int i = p >> 5, mq = p & 31;
    *reinterpret_cast<bf8_t*>(&As[i][mq * 8]) =
        *reinterpret_cast<const bf8_t*>(ag + (R + i) * 1024 + F + mq * 8);
    *reinterpret_cast<bf8_t*>(&Vs[i][mq * 8]) =
        *reinterpret_cast<const bf8_t*>(vg + (R + i) * 1024 + F + mq * 8);
  }
  for (int j = 0; j < 18; j++) {
    int p = tid + 256 * j;
    if (p < 64 * 72) {
      int t = p / 72, i = p % 72;
      Ls[t][i] = (i <= t) ? (__bf16)1.0f : (__bf16)0.0f;
    }
  }
  zs[tid] = Zp[((size_t)bh * NC + c) * 256 + tid];
  gns[tid] = gnw[tid];
  __syncthreads();

  const f4_t fzero = {0.f, 0.f, 0.f, 0.f};
  const __bf16* qrow = qg + (R + wvid * 16 + l16) * 1024 + F;

  // phase A: S1 = Q K^T  (intra-chunk)
  f4_t s1a[4];
  #pragma unroll
  for (int it = 0; it < 4; it++) s1a[it] = fzero;
  #pragma unroll
  for (int ks = 0; ks < 8; ks++) {
    bf8_t aq = *reinterpret_cast<const bf8_t*>(qrow + ks * 32 + quad * 8);
    #pragma unroll
    for (int it = 0; it < 4; it++) {
      bf8_t bk = *reinterpret_cast<const bf8_t*>(
          kg + (R + it * 16 + l16) * 1024 + F + ks * 32 + quad * 8);
      s1a[it] = mfma16(aq, bk, s1a[it]);
    }
  }
  #pragma unroll
  for (int it = 0; it < 4; it++)
    #pragma unroll
    for (int r = 0; r < 4; r++) {
      int tl = wvid * 16 + quad * 4 + r;
      int il = it * 16 + l16;
      S1s[tl][il] = (il <= tl) ? (__bf16)s1a[it][r] : (__bf16)0.0f;
    }
  __syncthreads();

  // phase B: intra numerator (S1_masked @ A) and cumA (L @ A)
  f4_t aok[16], acum[16];
  #pragma unroll
  for (int mt = 0; mt < 16; mt++) { aok[mt] = fzero; acum[mt] = fzero; }
  #pragma unroll
  for (int iks = 0; iks < 2; iks++) {
    bf8_t s1f = *reinterpret_cast<const bf8_t*>(&S1s[wvid * 16 + l16][iks * 32 + quad * 8]);
    bf8_t lf  = *reinterpret_cast<const bf8_t*>(&Ls [wvid * 16 + l16][iks * 32 + quad * 8]);
    #pragma unroll
    for (int mt = 0; mt < 16; mt++) {
      bf8_t bfa;
      #pragma unroll
      for (int w = 0; w < 8; w++) {        // quad-swizzled transposed reads
        int j = (w + 2 * quad) & 7;
        bfa[j] = As[iks * 32 + quad * 8 + j][mt * 16 + l16];
      }
      aok[mt]  = mfma16(s1f, bfa, aok[mt]);
      acum[mt] = mfma16(lf,  bfa, acum[mt]);
    }
  }
  // phase C: cross numerator  Q @ HKpre
  const __bf16* hkb = HKp + ((size_t)bh * NC + c) * 65536;
  #pragma unroll
  for (int ks = 0; ks < 8; ks++) {
    bf8_t aq = *reinterpret_cast<const bf8_t*>(qrow + ks * 32 + quad * 8);
    #pragma unroll
    for (int mt = 0; mt < 16; mt++) {
      bf8_t bv = *reinterpret_cast<const bf8_t*>(
          hkb + (size_t)(mt * 16 + l16) * 256 + ks * 32 + quad * 8);
      aok[mt] = mfma16(aq, bv, aok[mt]);
    }
  }
  // softmax over m ; W = qv / SumA
  #pragma unroll
  for (int r = 0; r < 4; r++) {
    float ovv[16], sa[16];
    float mx = -3.0e38f;
    #pragma unroll
    for (int mt = 0; mt < 16; mt++) {
      sa[mt] = zs[mt * 16 + l16] + acum[mt][r];
      ovv[mt] = SCALE * aok[mt][r] / sa[mt];
      mx = fmaxf(mx, ovv[mt]);
    }
    #pragma unroll
    for (int off = 1; off < 16; off <<= 1) mx = fmaxf(mx, __shfl_xor(mx, off));
    float se = 0.f;
    #pragma unroll
    for (int mt = 0; mt < 16; mt++) { ovv[mt] = __expf(ovv[mt] - mx); se += ovv[mt]; }
    #pragma unroll
    for (int off = 1; off < 16; off <<= 1) se += __shfl_xor(se, off);
    float inv = 1.0f / se;
    int tl = wvid * 16 + quad * 4 + r;
    #pragma unroll
    for (int mt = 0; mt < 16; mt++)
      Ws[tl][mt * 16 + l16] = (__bf16)(ovv[mt] * inv / sa[mt]);
  }
  __syncthreads();

  // phase 4a: P = mask(W @ A^T)
  f4_t pacc[4];
  #pragma unroll
  for (int it = 0; it < 4; it++) pacc[it] = fzero;
  #pragma unroll
  for (int ks = 0; ks < 8; ks++) {
    bf8_t wf = *reinterpret_cast<const bf8_t*>(&Ws[wvid * 16 + l16][ks * 32 + quad * 8]);
    #pragma unroll
    for (int it = 0; it < 4; it++) {
      bf8_t ba = *reinterpret_cast<const bf8_t*>(&As[it * 16 + l16][ks * 32 + quad * 8]);
      pacc[it] = mfma16(wf, ba, pacc[it]);
    }
  }
  #pragma unroll
  for (int it = 0; it < 4; it++)
    #pragma unroll
    for (int r = 0; r < 4; r++) {
      int tl = wvid * 16 + quad * 4 + r;
      int il = it * 16 + l16;
      S1s[tl][il] = (il <= tl) ? (__bf16)pacc[it][r] : (__bf16)0.0f;
    }
  __syncthreads();

  // phase 4b: O = W @ HVpre^T + P @ V
  f4_t oacc[16];
  #pragma unroll
  for (int vt = 0; vt < 16; vt++) oacc[vt] = fzero;
  const __bf16* hvb = HVp + ((size_t)bh * NC + c) * 65536;
  #pragma unroll
  for (int ks = 0; ks < 8; ks++) {
    bf8_t wf = *reinterpret_cast<const bf8_t*>(&Ws[wvid * 16 + l16][ks * 32 + quad * 8]);
    #pragma unroll
    for (int vt = 0; vt < 16; vt++) {
      bf8_t bv = *reinterpret_cast<const bf8_t*>(
          hvb + (size_t)(vt * 16 + l16) * 256 + ks * 32 + quad * 8);
      oacc[vt] = mfma16(wf, bv, oacc[vt]);
    }
  }
  #pragma unroll
  for (int iks = 0; iks < 2; iks++) {
    bf8_t pf = *reinterpret_cast<const bf8_t*>(&S1s[wvid * 16 + l16][iks * 32 + quad * 8]);
    #pragma unroll
    for (int vt = 0; vt < 16; vt++) {
      bf8_t bvt;
      #pragma unroll
      for (int w = 0; w < 8; w++) {
        int j = (w + 2 * quad) & 7;
        bvt[j] = Vs[iks * 32 + quad * 8 + j][vt * 16 + l16];
      }
      oacc[vt] = mfma16(pf, bvt, oacc[vt]);
    }
  }
  // epilogue: fused RMSNorm * gn_w * g * sigmoid(g) -> y (bf16)
  #pragma unroll
  for (int r = 0; r < 4; r++) {
    float ss = 0.f;
    #pragma unroll
    for (int vt = 0; vt < 16; vt++) ss += oacc[vt][r] * oacc[vt][r];
    #pragma unroll
    for (int off = 1; off < 16; off <<= 1) ss += __shfl_xor(ss, off);
    float rinv = rsqrtf(ss * (1.0f / 256.0f) + EPS);
    int tl = wvid * 16 + quad * 4 + r;
    const __bf16* grow = gg + (R + tl) * 1024 + F;
    __bf16* yrow = yout + (R + tl) * 1024 + F;
    #pragma unroll
    for (int vt = 0; vt < 16; vt++) {
      int v = vt * 16 + l16;
      float gvl = (float)grow[v];
      float yv = oacc[vt][r] * rinv * gns[v] * gvl / (1.0f + __expf(-gvl));
      yrow[v] = (__bf16)yv;
    }
  }
}

// ---------------------------------------------------------------------------
extern "C" void kernel_launch(void* const* d_in, const int* in_sizes, int n_in,
                              void* d_out, int out_size, void* d_ws, size_t ws_size,
                              hipStream_t stream) {
  using namespace abc;
  (void)in_sizes; (void)n_in; (void)out_size; (void)ws_size;
  const float* x    = (const float*)d_in[0];
  const float* q_w  = (const float*)d_in[1];
  const float* k_w  = (const float*)d_in[2];
  const float* v_w  = (const float*)d_in[3];
  const float* g_w  = (const float*)d_in[4];
  const float* s_w  = (const float*)d_in[5];
  const float* sg_w = (const float*)d_in[6];
  const float* gn_w = (const float*)d_in[7];
  const float* o_w  = (const float*)d_in[8];
  float* out = (float*)d_out;

  char* ws = (char*)d_ws;
  const size_t PROJ = (size_t)BT * 1024;       // elements per projection
  __bf16* proj = (__bf16*)ws;                  // q,k,v,g,a + shared xb/y slot
  __bf16* q_bf = proj + 0 * PROJ;
  __bf16* k_bf = proj + 1 * PROJ;
  __bf16* v_bf = proj + 2 * PROJ;
  __bf16* g_bf = proj + 3 * PROJ;
  __bf16* a_bf = proj + 4 * PROJ;
  __bf16* xb   = proj + 5 * PROJ;              // x bf16; dead after proj gemm
  __bf16* y_bf = proj + 5 * PROJ;              // reuses xb slot (attn output)
  float* sgl = (float*)(ws + (size_t)96 * 1024 * 1024);
  float* sgc = sgl + (size_t)BH * T;
  float* csA = sgc + (size_t)BH * T;           // 16*32*256 floats
  __bf16* HKc = (__bf16*)(ws + (size_t)97 * 1024 * 1024);   // 64MB
  __bf16* HVc = HKc + (size_t)BH * NC * 65536;               // 64MB
  __bf16* wt  = (__bf16*)(ws + (size_t)225 * 1024 * 1024);  // 6 x 1M bf16 = 12MB

  dim3 blk(256);
  cvt_w_kernel<<<dim3(16, 16, 6), blk, 0, stream>>>(q_w, k_w, v_w, g_w, s_w, o_w, wt);
  cvt_x_kernel<<<dim3(BT * 1024 / (256 * 8)), blk, 0, stream>>>(x, xb);
  gemm_bt_kernel<true><<<dim3(8, 64, 5), blk, 0, stream>>>(xb, wt, proj);
  sg_kernel<<<dim3(BT / 4), blk, 0, stream>>>(x, sg_w, sgl);
  scan_kernel<<<dim3(BH), blk, 0, stream>>>(sgl, sgc);
  prep_kernel<<<dim3(BT), blk, 0, stream>>>(q_bf, k_bf, a_bf, sgc);
  chunkstate_kernel<<<dim3(NC, BH, 4), blk, 0, stream>>>(
      k_bf, v_bf, a_bf, HKc, HVc, csA);
  prefix_state_kernel<<<dim3(64, BH, 2), blk, 0, stream>>>(HKc, HVc);
  prefix_csa_kernel<<<dim3(BH), blk, 0, stream>>>(csA);
  attn_kernel<<<dim3(NC, BH), blk, 0, stream>>>(
      q_bf, k_bf, v_bf, a_bf, g_bf, HKc, HVc, csA, gn_w, y_bf);
  gemm_bt_kernel<false><<<dim3(8, 64, 1), blk, 0, stream>>>(
      y_bf, wt + (size_t)5 * 1024 * 1024, out);
}

// Round 3
// 632.734 us; speedup vs baseline: 1.4881x; 1.0366x over previous
//
#include <hip/hip_runtime.h>
#include <hip/hip_bf16.h>
#include <stdint.h>
#include <stddef.h>
#include <math.h>

typedef __bf16 bf8_t __attribute__((ext_vector_type(8)));
typedef __bf16 bf4_t __attribute__((ext_vector_type(4)));
typedef float  f4_t  __attribute__((ext_vector_type(4)));
typedef unsigned int u32;

#define DEV static __device__ __forceinline__

namespace abc {
constexpr int B = 4, T = 2048, D = 1024, H = 4;
constexpr int BT = B * T;          // 8192
constexpr int CH = 64;             // chunk length
constexpr int NC = T / CH;         // 32 chunks
constexpr int BH = B * H;          // 16
constexpr float SCALE = 0.0625f;   // DK^-0.5
constexpr float GN = 16.0f;
constexpr float EPS = 1e-5f;
}

DEV f4_t mfma16(bf8_t a, bf8_t b, f4_t c) {
  return __builtin_amdgcn_mfma_f32_16x16x32_bf16(a, b, c, 0, 0, 0);
}

// async global->LDS, 16B per lane; lds dest must be wave-uniform base (+lane*16)
DEV void glds16(const void* g, void* l) {
  __builtin_amdgcn_global_load_lds(
      (const __attribute__((address_space(1))) u32*)g,
      (__attribute__((address_space(3))) u32*)l, 16, 0, 0);
}

// ---------------------------------------------------------------------------
// x fp32 -> bf16 (row-major unchanged). 8 elems/thread.
// ---------------------------------------------------------------------------
__global__ __launch_bounds__(256)
void cvt_x_kernel(const float* __restrict__ x, __bf16* __restrict__ xb)
{
  const int idx = blockIdx.x * 256 + threadIdx.x;   // 1M threads total
  const float4* src = reinterpret_cast<const float4*>(x);
  float4 a = src[(size_t)idx * 2];
  float4 b = src[(size_t)idx * 2 + 1];
  bf8_t o;
  o[0] = (__bf16)a.x; o[1] = (__bf16)a.y; o[2] = (__bf16)a.z; o[3] = (__bf16)a.w;
  o[4] = (__bf16)b.x; o[5] = (__bf16)b.y; o[6] = (__bf16)b.z; o[7] = (__bf16)b.w;
  reinterpret_cast<bf8_t*>(xb)[idx] = o;
}

// ---------------------------------------------------------------------------
// weight fp32 [k][n] -> bf16 [n][k] (transpose), 64x64 tiles, 6 weights
// ---------------------------------------------------------------------------
__global__ __launch_bounds__(256)
void cvt_w_kernel(const float* __restrict__ w0, const float* __restrict__ w1,
                  const float* __restrict__ w2, const float* __restrict__ w3,
                  const float* __restrict__ w4, const float* __restrict__ w5,
                  __bf16* __restrict__ wt)
{
  const int z = blockIdx.z;
  const float* W = (z == 0) ? w0 : (z == 1) ? w1 : (z == 2) ? w2
                 : (z == 3) ? w3 : (z == 4) ? w4 : w5;
  const int n0 = blockIdx.x * 64, k0 = blockIdx.y * 64;
  __shared__ __bf16 Ts[64][72];
  const int tid = threadIdx.x;
  #pragma unroll
  for (int i = 0; i < 4; i++) {
    int p = tid + 256 * i;            // 1024 float4 chunks: 64 k-rows x 16
    int row = p >> 4, c4 = p & 15;
    float4 v = *reinterpret_cast<const float4*>(W + (size_t)(k0 + row) * 1024 + n0 + c4 * 4);
    Ts[c4 * 4 + 0][row] = (__bf16)v.x;
    Ts[c4 * 4 + 1][row] = (__bf16)v.y;
    Ts[c4 * 4 + 2][row] = (__bf16)v.z;
    Ts[c4 * 4 + 3][row] = (__bf16)v.w;
  }
  __syncthreads();
  #pragma unroll
  for (int i = 0; i < 2; i++) {
    int p = tid + 256 * i;            // 512 bf8 chunks: 64 n-rows x 8
    int n = p >> 3, kq = p & 7;
    bf8_t o = *reinterpret_cast<const bf8_t*>(&Ts[n][kq * 8]);
    *reinterpret_cast<bf8_t*>(wt + (size_t)z * 1024 * 1024 + (size_t)(n0 + n) * 1024 + k0 + kq * 8) = o;
  }
}

// ---------------------------------------------------------------------------
// m97-style GEMM: C[8192 x 1024] = A[8192 x 1024] * Bt[z][n][k]^T
// 128x128 tile, BK=64, global_load_lds width-16 staging, unpadded LDS.
// ---------------------------------------------------------------------------
template<bool OUT_BF16>
__global__ __launch_bounds__(256)
void gemm_bt_kernel(const __bf16* __restrict__ A, const __bf16* __restrict__ BtB,
                    void* __restrict__ Cp)
{
  using namespace abc;
  constexpr int K = 1024;
  const int z = blockIdx.z;
  const __bf16* Bt = BtB + (size_t)z * K * 1024;
  const int n0 = blockIdx.x * 128;
  const int m0 = blockIdx.y * 128;
  __shared__ __bf16 As[128 * 64];   // [m][k], unpadded (global_load_lds layout)
  __shared__ __bf16 Bs[128 * 64];   // [n][k]
  const int tid = threadIdx.x;
  const int lane = tid & 63, wvid = tid >> 6;
  const int wr = wvid >> 1, wc = wvid & 1;
  const int quad = lane >> 4, l16 = lane & 15;
  const f4_t fzero = {0.f, 0.f, 0.f, 0.f};
  f4_t acc[4][4];
  #pragma unroll
  for (int i = 0; i < 4; i++)
    #pragma unroll
    for (int j = 0; j < 4; j++) acc[i][j] = fzero;

  const int chunk_row = tid >> 3;          // 0..31 within each i-group of 32 rows
  const int chunk_col = tid & 7;           // 8 x 16B per 128B row
  for (int k0 = 0; k0 < K; k0 += 64) {
    __syncthreads();
    #pragma unroll
    for (int i = 0; i < 4; i++) {
      glds16(A + (size_t)(m0 + i * 32 + chunk_row) * K + k0 + chunk_col * 8,
             &As[(size_t)(i * 256 + wvid * 64) * 8]);
    }
    #pragma unroll
    for (int i = 0; i < 4; i++) {
      glds16(Bt + (size_t)(n0 + i * 32 + chunk_row) * K + k0 + chunk_col * 8,
             &Bs[(size_t)(i * 256 + wvid * 64) * 8]);
    }
    __syncthreads();
    #pragma unroll
    for (int ks = 0; ks < 2; ks++) {
      bf8_t af[4], bfv[4];
      #pragma unroll
      for (int i = 0; i < 4; i++)
        af[i] = *reinterpret_cast<const bf8_t*>(
            &As[(size_t)(wr * 64 + i * 16 + l16) * 64 + ks * 32 + quad * 8]);
      #pragma unroll
      for (int j = 0; j < 4; j++)
        bfv[j] = *reinterpret_cast<const bf8_t*>(
            &Bs[(size_t)(wc * 64 + j * 16 + l16) * 64 + ks * 32 + quad * 8]);
      #pragma unroll
      for (int i = 0; i < 4; i++)
        #pragma unroll
        for (int j = 0; j < 4; j++)
          acc[i][j] = mfma16(af[i], bfv[j], acc[i][j]);
    }
  }
  const int crow = m0 + wr * 64, ccol = n0 + wc * 64;
  if (OUT_BF16) {
    __bf16* C = (__bf16*)Cp + (size_t)z * BT * 1024;
    #pragma unroll
    for (int i = 0; i < 4; i++)
      #pragma unroll
      for (int j = 0; j < 4; j++)
        #pragma unroll
        for (int r = 0; r < 4; r++)
          C[(size_t)(crow + i * 16 + quad * 4 + r) * 1024 + ccol + j * 16 + l16] =
              (__bf16)acc[i][j][r];
  } else {
    float* C = (float*)Cp;
    #pragma unroll
    for (int i = 0; i < 4; i++)
      #pragma unroll
      for (int j = 0; j < 4; j++)
        #pragma unroll
        for (int r = 0; r < 4; r++)
          C[(size_t)(crow + i * 16 + quad * 4 + r) * 1024 + ccol + j * 16 + l16] =
              acc[i][j][r];
  }
}

// ---------------------------------------------------------------------------
// sg projection: sgl[bh][t] = log_sigmoid(x[b,t,:] . sg_w[:,h]) / 16
// ---------------------------------------------------------------------------
__global__ __launch_bounds__(256)
void sg_kernel(const float* __restrict__ x, const float* __restrict__ sgw,
               float* __restrict__ sgl)
{
  using namespace abc;
  const int wvid = threadIdx.x >> 6, lane = threadIdx.x & 63;
  const int bt = blockIdx.x * 4 + wvid;
  const float* xr = x + (size_t)bt * 1024;
  float a0 = 0, a1 = 0, a2 = 0, a3 = 0;
  #pragma unroll 4
  for (int u = 0; u < 16; u++) {
    int i = u * 64 + lane;
    float xv = xr[i];
    float4 w = *reinterpret_cast<const float4*>(sgw + (size_t)i * 4);
    a0 += xv * w.x; a1 += xv * w.y; a2 += xv * w.z; a3 += xv * w.w;
  }
  #pragma unroll
  for (int off = 32; off > 0; off >>= 1) {
    a0 += __shfl_down(a0, off);
    a1 += __shfl_down(a1, off);
    a2 += __shfl_down(a2, off);
    a3 += __shfl_down(a3, off);
  }
  if (lane == 0) {
    const int b = bt >> 11, t = bt & (T - 1);
    float r[4] = {a0, a1, a2, a3};
    #pragma unroll
    for (int h = 0; h < 4; h++) {
      float v = r[h];
      float ls = fminf(v, 0.f) - log1pf(expf(-fabsf(v)));
      sgl[(size_t)(b * 4 + h) * T + t] = ls * (1.0f / GN);
    }
  }
}

// ---------------------------------------------------------------------------
// inclusive cumsum over T per (b,h)
// ---------------------------------------------------------------------------
__global__ __launch_bounds__(256)
void scan_kernel(const float* __restrict__ sgl, float* __restrict__ sgc)
{
  using namespace abc;
  const int bh = blockIdx.x;
  const float* in = sgl + (size_t)bh * T;
  float* out = sgc + (size_t)bh * T;
  __shared__ float part[256];
  const int tid = threadIdx.x;
  float v[8]; float s = 0.f;
  #pragma unroll
  for (int i = 0; i < 8; i++) { v[i] = in[tid * 8 + i]; s += v[i]; }
  part[tid] = s;
  __syncthreads();
  for (int off = 1; off < 256; off <<= 1) {
    float a = (tid >= off) ? part[tid - off] : 0.f;
    __syncthreads();
    part[tid] += a;
    __syncthreads();
  }
  float run = (tid > 0) ? part[tid - 1] : 0.f;
  #pragma unroll
  for (int i = 0; i < 8; i++) { run += v[i]; out[tid * 8 + i] = run; }
}

// ---------------------------------------------------------------------------
// prep: RoPE(q), RoPE(k)*exp(cumsum sg), s -> exp(clamp(s)) ; in-place on bf16
// ---------------------------------------------------------------------------
__global__ __launch_bounds__(256)
void prep_kernel(__bf16* __restrict__ q, __bf16* __restrict__ k,
                 __bf16* __restrict__ s, const float* __restrict__ sgc)
{
  using namespace abc;
  const int bt = blockIdx.x;
  const int b = bt >> 11, t = bt & (T - 1);
  const int tid = threadIdx.x;
  const size_t ro = (size_t)bt * 1024;
  #pragma unroll
  for (int i = 0; i < 2; i++) {
    int p = tid + 256 * i;          // 0..511 : h = p/128, d = p%128
    int h = p >> 7, d = p & 127;
    float inv = expf(-(float)d * (9.210340371976184f / 128.0f)); // 10000^(-d/128)
    float ang = (float)t * inv;
    float sn, cs;
    sincosf(ang, &sn, &cs);
    size_t base = ro + (size_t)h * 256 + d;
    float q1 = (float)q[base], q2 = (float)q[base + 128];
    q[base]       = (__bf16)(q1 * cs - q2 * sn);
    q[base + 128] = (__bf16)(q2 * cs + q1 * sn);
    float dec = expf(sgc[(size_t)(b * 4 + h) * T + t]);
    float k1 = (float)k[base], k2 = (float)k[base + 128];
    k[base]       = (__bf16)((k1 * cs - k2 * sn) * dec);
    k[base + 128] = (__bf16)((k2 * cs + k1 * sn) * dec);
  }
  #pragma unroll
  for (int i = 0; i < 4; i++) {
    int e = tid + 256 * i;
    float v = (float)s[ro + e];
    v = fminf(fmaxf(v, -32.f), 32.f);
    s[ro + e] = (__bf16)expf(v);
  }
}

// ---------------------------------------------------------------------------
// per-chunk states:
//   HKc[bh][c][m][k] = sum_t A[t][m] K[t][k]   (part 0/1: m-halves)
//   HVc[bh][c][v][m] = sum_t V[t][v] A[t][m]   (part 2/3: v-halves)
//   csA[bh][c][m]    = sum_t A[t][m]           (part 2)
//   AT[bh][c][m][t]  = A^T                     (part 0, from staged Xt)
// ---------------------------------------------------------------------------
__global__ __launch_bounds__(256)
void chunkstate_kernel(const __bf16* __restrict__ kg, const __bf16* __restrict__ vg,
                       const __bf16* __restrict__ ag,
                       __bf16* __restrict__ HKc, __bf16* __restrict__ HVc,
                       float* __restrict__ csA, __bf16* __restrict__ ATp)
{
  using namespace abc;
  const int c = blockIdx.x, bh = blockIdx.y, part = blockIdx.z;
  const int b = bh >> 2, h = bh & 3;
  const size_t R = (size_t)b * T + (size_t)c * CH;
  const int F = h * 256;
  const bool isHV = part >= 2;
  const int p2 = part & 1;
  const __bf16* Xsrc = isHV ? vg : ag;   // A-operand source (transposed)
  const __bf16* Ysrc = isHV ? ag : kg;   // B-operand source (transposed)
  __shared__ __bf16 Xt[256][72];
  __shared__ __bf16 Yt[256][72];
  const int tid = threadIdx.x;
  #pragma unroll
  for (int j = 0; j < 8; j++) {
    int p = tid + 256 * j;               // 2048 vec8 chunks over 64x256
    int i = p >> 5, fq = p & 31;
    bf8_t xv = *reinterpret_cast<const bf8_t*>(Xsrc + (R + i) * 1024 + F + fq * 8);
    bf8_t yv = *reinterpret_cast<const bf8_t*>(Ysrc + (R + i) * 1024 + F + fq * 8);
    #pragma unroll
    for (int u = 0; u < 8; u++) { Xt[fq * 8 + u][i] = xv[u]; Yt[fq * 8 + u][i] = yv[u]; }
  }
  __syncthreads();
  if (part == 2) {
    float ssum = 0.f;
    #pragma unroll 8
    for (int t = 0; t < CH; t++) ssum += (float)Yt[tid][t];
    csA[((size_t)bh * NC + c) * 256 + tid] = ssum;
  }
  if (part == 0) {
    __bf16* atb = ATp + ((size_t)bh * NC + c) * (256 * 64);
    #pragma unroll
    for (int j = 0; j < 8; j++) {
      int p = tid + 256 * j;             // 2048 bf8 chunks: 256 rows x 8
      int row = p >> 3, kq = p & 7;
      *reinterpret_cast<bf8_t*>(atb + (size_t)row * 64 + kq * 8) =
          *reinterpret_cast<const bf8_t*>(&Xt[row][kq * 8]);
    }
  }
  const int lane = tid & 63, wvid = tid >> 6;
  const int quad = lane >> 4, l16 = lane & 15;
  const int row0 = p2 * 128 + wvid * 32;
  const f4_t fzero = {0.f, 0.f, 0.f, 0.f};
  f4_t acc[2][16];
  #pragma unroll
  for (int a = 0; a < 2; a++)
    #pragma unroll
    for (int ct = 0; ct < 16; ct++) acc[a][ct] = fzero;
  #pragma unroll
  for (int ks = 0; ks < 2; ks++) {
    bf8_t af0 = *reinterpret_cast<const bf8_t*>(&Xt[row0 + l16][ks * 32 + quad * 8]);
    bf8_t af1 = *reinterpret_cast<const bf8_t*>(&Xt[row0 + 16 + l16][ks * 32 + quad * 8]);
    #pragma unroll
    for (int ct = 0; ct < 16; ct++) {
      bf8_t bv = *reinterpret_cast<const bf8_t*>(&Yt[ct * 16 + l16][ks * 32 + quad * 8]);
      acc[0][ct] = mfma16(af0, bv, acc[0][ct]);
      acc[1][ct] = mfma16(af1, bv, acc[1][ct]);
    }
  }
  __bf16* out = (isHV ? HVc : HKc) + ((size_t)bh * NC + c) * 65536;
  #pragma unroll
  for (int rt = 0; rt < 2; rt++)
    #pragma unroll
    for (int ct = 0; ct < 16; ct++)
      #pragma unroll
      for (int r = 0; r < 4; r++)
        out[(size_t)(row0 + rt * 16 + quad * 4 + r) * 256 + ct * 16 + l16] =
            (__bf16)acc[rt][ct][r];
}

// ---------------------------------------------------------------------------
// in-place exclusive prefix over chunk axis of HKc/HVc (bf16, fp32 run)
// ---------------------------------------------------------------------------
__global__ __launch_bounds__(256)
void prefix_state_kernel(__bf16* __restrict__ HKc, __bf16* __restrict__ HVc)
{
  using namespace abc;
  const int bh = blockIdx.y;
  __bf16* base = (blockIdx.z ? HVc : HKc) + (size_t)bh * NC * 65536;
  const int e = (blockIdx.x * 256 + threadIdx.x) * 4;
  float run0 = 0, run1 = 0, run2 = 0, run3 = 0;
  for (int c = 0; c < NC; c++) {
    __bf16* p = base + (size_t)c * 65536 + e;
    bf4_t v = *reinterpret_cast<const bf4_t*>(p);
    bf4_t o;
    o[0] = (__bf16)run0; o[1] = (__bf16)run1; o[2] = (__bf16)run2; o[3] = (__bf16)run3;
    run0 += (float)v[0]; run1 += (float)v[1]; run2 += (float)v[2]; run3 += (float)v[3];
    *reinterpret_cast<bf4_t*>(p) = o;
  }
}

__global__ __launch_bounds__(256)
void prefix_csa_kernel(float* __restrict__ csA)
{
  using namespace abc;
  const int bh = blockIdx.x, m = threadIdx.x;
  float run = 0.f;
  for (int c = 0; c < NC; c++) {
    float* p = csA + ((size_t)bh * NC + c) * 256 + m;
    float v = *p; *p = run; run += v;
  }
}

// ---------------------------------------------------------------------------
// main chunked ABC attention + fused RMSNorm/SiLU-gate epilogue
// one block per (chunk, bh); each wave owns a 16-row strip; LDS = 80 KB
// (2 blocks/CU). S1s/Ws are per-wave-strip: no cross-wave barriers needed.
// ---------------------------------------------------------------------------
__global__ __launch_bounds__(256)
void attn_kernel(const __bf16* __restrict__ qg, const __bf16* __restrict__ kg,
                 const __bf16* __restrict__ vg, const __bf16* __restrict__ ag,
                 const __bf16* __restrict__ gg, const __bf16* __restrict__ ATp,
                 const __bf16* __restrict__ HKp, const __bf16* __restrict__ HVp,
                 const float* __restrict__ Zp, const float* __restrict__ gnw,
                 __bf16* __restrict__ yout)
{
  using namespace abc;
  const int c = blockIdx.x, bh = blockIdx.y;
  const int b = bh >> 2, h = bh & 3;
  const size_t R = (size_t)b * T + (size_t)c * CH;
  const int F = h * 256;
  const int tid = threadIdx.x;
  const int lane = tid & 63, wvid = tid >> 6;
  const int quad = lane >> 4, l16 = lane & 15;

  __shared__ __bf16 Vst[256][72];  // V^T (transposed at load)
  __shared__ __bf16 Ws[64][264];   // W = qv / SumA (per-wave strip)
  __shared__ __bf16 S1s[64][72];   // masked QK^T, later masked P (per-wave strip)
  __shared__ float zs[256];
  __shared__ float gns[256];

  #pragma unroll
  for (int j = 0; j < 8; j++) {
    int p = tid + 256 * j;
    int i = p >> 5, fq = p & 31;
    bf8_t vv = *reinterpret_cast<const bf8_t*>(vg + (R + i) * 1024 + F + fq * 8);
    #pragma unroll
    for (int u = 0; u < 8; u++) Vst[fq * 8 + u][i] = vv[u];
  }
  zs[tid] = Zp[((size_t)bh * NC + c) * 256 + tid];
  gns[tid] = gnw[tid];
  __syncthreads();   // the only barrier: Vst/zs/gns shared across waves

  const f4_t fzero = {0.f, 0.f, 0.f, 0.f};
  const __bf16* qrow = qg + (R + wvid * 16 + l16) * 1024 + F;

  // phase A: S1 = Q K^T (intra-chunk), frags straight from global
  f4_t s1a[4];
  #pragma unroll
  for (int it = 0; it < 4; it++) s1a[it] = fzero;
  #pragma unroll
  for (int ks = 0; ks < 8; ks++) {
    bf8_t aq = *reinterpret_cast<const bf8_t*>(qrow + ks * 32 + quad * 8);
    #pragma unroll
    for (int it = 0; it < 4; it++) {
      bf8_t bk = *reinterpret_cast<const bf8_t*>(
          kg + (R + it * 16 + l16) * 1024 + F + ks * 32 + quad * 8);
      s1a[it] = mfma16(aq, bk, s1a[it]);
    }
  }
  #pragma unroll
  for (int it = 0; it < 4; it++)
    #pragma unroll
    for (int r = 0; r < 4; r++) {
      int tl = wvid * 16 + quad * 4 + r;
      int il = it * 16 + l16;
      S1s[tl][il] = (il <= tl) ? (__bf16)s1a[it][r] : (__bf16)0.0f;
    }

  // phase B: intra numerator (S1_masked @ A) and cumA (L @ A); A^T from global
  const __bf16* atb = ATp + ((size_t)bh * NC + c) * (256 * 64);
  f4_t aok[16], acum[16];
  #pragma unroll
  for (int mt = 0; mt < 16; mt++) { aok[mt] = fzero; acum[mt] = fzero; }
  #pragma unroll
  for (int iks = 0; iks < 2; iks++) {
    bf8_t s1f = *reinterpret_cast<const bf8_t*>(&S1s[wvid * 16 + l16][iks * 32 + quad * 8]);
    bf8_t lf;                        // lower-tri ones, built in registers
    #pragma unroll
    for (int j = 0; j < 8; j++)
      lf[j] = (iks * 32 + quad * 8 + j <= wvid * 16 + l16) ? (__bf16)1.0f : (__bf16)0.0f;
    #pragma unroll
    for (int mt = 0; mt < 16; mt++) {
      bf8_t bfa = *reinterpret_cast<const bf8_t*>(
          atb + (size_t)(mt * 16 + l16) * 64 + iks * 32 + quad * 8);
      aok[mt]  = mfma16(s1f, bfa, aok[mt]);
      acum[mt] = mfma16(lf,  bfa, acum[mt]);
    }
  }
  // phase C: cross numerator  Q @ HKpre
  const __bf16* hkb = HKp + ((size_t)bh * NC + c) * 65536;
  #pragma unroll
  for (int ks = 0; ks < 8; ks++) {
    bf8_t aq = *reinterpret_cast<const bf8_t*>(qrow + ks * 32 + quad * 8);
    #pragma unroll
    for (int mt = 0; mt < 16; mt++) {
      bf8_t bv = *reinterpret_cast<const bf8_t*>(
          hkb + (size_t)(mt * 16 + l16) * 256 + ks * 32 + quad * 8);
      aok[mt] = mfma16(aq, bv, aok[mt]);
    }
  }
  // softmax over m ; W = qv / SumA  (16-lane quad-group reductions)
  #pragma unroll
  for (int r = 0; r < 4; r++) {
    float ovv[16], sa[16];
    float mx = -3.0e38f;
    #pragma unroll
    for (int mt = 0; mt < 16; mt++) {
      sa[mt] = zs[mt * 16 + l16] + acum[mt][r];
      ovv[mt] = SCALE * aok[mt][r] / sa[mt];
      mx = fmaxf(mx, ovv[mt]);
    }
    #pragma unroll
    for (int off = 1; off < 16; off <<= 1) mx = fmaxf(mx, __shfl_xor(mx, off));
    float se = 0.f;
    #pragma unroll
    for (int mt = 0; mt < 16; mt++) { ovv[mt] = __expf(ovv[mt] - mx); se += ovv[mt]; }
    #pragma unroll
    for (int off = 1; off < 16; off <<= 1) se += __shfl_xor(se, off);
    float inv = 1.0f / se;
    int tl = wvid * 16 + quad * 4 + r;
    #pragma unroll
    for (int mt = 0; mt < 16; mt++)
      Ws[tl][mt * 16 + l16] = (__bf16)(ovv[mt] * inv / sa[mt]);
  }

  // phase 4a: P = mask(W @ A^T); B-op = A natural rows from global
  f4_t pacc[4];
  #pragma unroll
  for (int it = 0; it < 4; it++) pacc[it] = fzero;
  #pragma unroll
  for (int ks = 0; ks < 8; ks++) {
    bf8_t wf = *reinterpret_cast<const bf8_t*>(&Ws[wvid * 16 + l16][ks * 32 + quad * 8]);
    #pragma unroll
    for (int it = 0; it < 4; it++) {
      bf8_t ba = *reinterpret_cast<const bf8_t*>(
          ag + (R + it * 16 + l16) * 1024 + F + ks * 32 + quad * 8);
      pacc[it] = mfma16(wf, ba, pacc[it]);
    }
  }
  #pragma unroll
  for (int it = 0; it < 4; it++)
    #pragma unroll
    for (int r = 0; r < 4; r++) {
      int tl = wvid * 16 + quad * 4 + r;
      int il = it * 16 + l16;
      S1s[tl][il] = (il <= tl) ? (__bf16)pacc[it][r] : (__bf16)0.0f;
    }

  // phase 4b: O = W @ HVpre^T + P @ V  (V^T natural rows from LDS)
  f4_t oacc[16];
  #pragma unroll
  for (int vt = 0; vt < 16; vt++) oacc[vt] = fzero;
  const __bf16* hvb = HVp + ((size_t)bh * NC + c) * 65536;
  #pragma unroll
  for (int ks = 0; ks < 8; ks++) {
    bf8_t wf = *reinterpret_cast<const bf8_t*>(&Ws[wvid * 16 + l16][ks * 32 + quad * 8]);
    #pragma unroll
    for (int vt = 0; vt < 16; vt++) {
      bf8_t bv = *reinterpret_cast<const bf8_t*>(
          hvb + (size_t)(vt * 16 + l16) * 256 + ks * 32 + quad * 8);
      oacc[vt] = mfma16(wf, bv, oacc[vt]);
    }
  }
  #pragma unroll
  for (int iks = 0; iks < 2; iks++) {
    bf8_t pf = *reinterpret_cast<const bf8_t*>(&S1s[wvid * 16 + l16][iks * 32 + quad * 8]);
    #pragma unroll
    for (int vt = 0; vt < 16; vt++) {
      bf8_t bvt = *reinterpret_cast<const bf8_t*>(&Vst[vt * 16 + l16][iks * 32 + quad * 8]);
      oacc[vt] = mfma16(pf, bvt, oacc[vt]);
    }
  }
  // epilogue: fused RMSNorm * gn_w * g * sigmoid(g) -> y (bf16)
  #pragma unroll
  for (int r = 0; r < 4; r++) {
    float ss = 0.f;
    #pragma unroll
    for (int vt = 0; vt < 16; vt++) ss += oacc[vt][r] * oacc[vt][r];
    #pragma unroll
    for (int off = 1; off < 16; off <<= 1) ss += __shfl_xor(ss, off);
    float rinv = rsqrtf(ss * (1.0f / 256.0f) + EPS);
    int tl = wvid * 16 + quad * 4 + r;
    const __bf16* grow = gg + (R + tl) * 1024 + F;
    __bf16* yrow = yout + (R + tl) * 1024 + F;
    #pragma unroll
    for (int vt = 0; vt < 16; vt++) {
      int v = vt * 16 + l16;
      float gvl = (float)grow[v];
      float yv = oacc[vt][r] * rinv * gns[v] * gvl / (1.0f + __expf(-gvl));
      yrow[v] = (__bf16)yv;
    }
  }
}

// ---------------------------------------------------------------------------
extern "C" void kernel_launch(void* const* d_in, const int* in_sizes, int n_in,
                              void* d_out, int out_size, void* d_ws, size_t ws_size,
                              hipStream_t stream) {
  using namespace abc;
  (void)in_sizes; (void)n_in; (void)out_size; (void)ws_size;
  const float* x    = (const float*)d_in[0];
  const float* q_w  = (const float*)d_in[1];
  const float* k_w  = (const float*)d_in[2];
  const float* v_w  = (const float*)d_in[3];
  const float* g_w  = (const float*)d_in[4];
  const float* s_w  = (const float*)d_in[5];
  const float* sg_w = (const float*)d_in[6];
  const float* gn_w = (const float*)d_in[7];
  const float* o_w  = (const float*)d_in[8];
  float* out = (float*)d_out;

  char* ws = (char*)d_ws;
  const size_t PROJ = (size_t)BT * 1024;       // elements per projection
  __bf16* proj = (__bf16*)ws;                  // q,k,v,g,a + shared xb/y slot
  __bf16* q_bf = proj + 0 * PROJ;
  __bf16* k_bf = proj + 1 * PROJ;
  __bf16* v_bf = proj + 2 * PROJ;
  __bf16* g_bf = proj + 3 * PROJ;
  __bf16* a_bf = proj + 4 * PROJ;
  __bf16* xb   = proj + 5 * PROJ;              // x bf16; dead after proj gemm
  __bf16* y_bf = proj + 5 * PROJ;              // reuses xb slot (attn output)
  float* sgl = (float*)(ws + (size_t)96 * 1024 * 1024);
  float* sgc = sgl + (size_t)BH * T;
  float* csA = sgc + (size_t)BH * T;           // 16*32*256 floats
  __bf16* HKc = (__bf16*)(ws + (size_t)97 * 1024 * 1024);   // 64MB
  __bf16* HVc = HKc + (size_t)BH * NC * 65536;               // 64MB
  __bf16* wt  = (__bf16*)(ws + (size_t)225 * 1024 * 1024);  // 6 x 1M bf16 = 12MB
  __bf16* AT  = (__bf16*)(ws + (size_t)237 * 1024 * 1024);  // 16MB A^T tiles

  dim3 blk(256);
  cvt_w_kernel<<<dim3(16, 16, 6), blk, 0, stream>>>(q_w, k_w, v_w, g_w, s_w, o_w, wt);
  cvt_x_kernel<<<dim3(BT * 1024 / (256 * 8)), blk, 0, stream>>>(x, xb);
  gemm_bt_kernel<true><<<dim3(8, 64, 5), blk, 0, stream>>>(xb, wt, proj);
  sg_kernel<<<dim3(BT / 4), blk, 0, stream>>>(x, sg_w, sgl);
  scan_kernel<<<dim3(BH), blk, 0, stream>>>(sgl, sgc);
  prep_kernel<<<dim3(BT), blk, 0, stream>>>(q_bf, k_bf, a_bf, sgc);
  chunkstate_kernel<<<dim3(NC, BH, 4), blk, 0, stream>>>(
      k_bf, v_bf, a_bf, HKc, HVc, csA, AT);
  prefix_state_kernel<<<dim3(64, BH, 2), blk, 0, stream>>>(HKc, HVc);
  prefix_csa_kernel<<<dim3(BH), blk, 0, stream>>>(csA);
  attn_kernel<<<dim3(NC, BH), blk, 0, stream>>>(
      q_bf, k_bf, v_bf, a_bf, g_bf, AT, HKc, HVc, csA, gn_w, y_bf);
  gemm_bt_kernel<false><<<dim3(8, 64, 1), blk, 0, stream>>>(
      y_bf, wt + (size_t)5 * 1024 * 1024, out);
}

// Round 5
// 568.794 us; speedup vs baseline: 1.6553x; 1.1124x over previous
//
#include <hip/hip_runtime.h>
#include <hip/hip_bf16.h>
#include <stdint.h>
#include <stddef.h>
#include <math.h>

typedef __bf16 bf8_t __attribute__((ext_vector_type(8)));
typedef __bf16 bf4_t __attribute__((ext_vector_type(4)));
typedef float  f4_t  __attribute__((ext_vector_type(4)));
typedef unsigned int u32;

#define DEV static __device__ __forceinline__

namespace abc {
constexpr int B = 4, T = 2048, D = 1024, H = 4;
constexpr int BT = B * T;          // 8192
constexpr int CH = 64;             // chunk length
constexpr int NC = T / CH;         // 32 chunks
constexpr int BH = B * H;          // 16
constexpr float SCALE = 0.0625f;   // DK^-0.5
constexpr float GN = 16.0f;
constexpr float EPS = 1e-5f;
}

DEV f4_t mfma16(bf8_t a, bf8_t b, f4_t c) {
  return __builtin_amdgcn_mfma_f32_16x16x32_bf16(a, b, c, 0, 0, 0);
}

// async global->LDS, 16B per lane; lds dest must be wave-uniform base (+lane*16)
DEV void glds16(const void* g, void* l) {
  __builtin_amdgcn_global_load_lds(
      (const __attribute__((address_space(1))) u32*)g,
      (__attribute__((address_space(3))) u32*)l, 16, 0, 0);
}

// ---------------------------------------------------------------------------
// x fp32 -> bf16 (row-major unchanged). 8 elems/thread.
// ---------------------------------------------------------------------------
__global__ __launch_bounds__(256)
void cvt_x_kernel(const float* __restrict__ x, __bf16* __restrict__ xb)
{
  const int idx = blockIdx.x * 256 + threadIdx.x;   // 1M threads total
  const float4* src = reinterpret_cast<const float4*>(x);
  float4 a = src[(size_t)idx * 2];
  float4 b = src[(size_t)idx * 2 + 1];
  bf8_t o;
  o[0] = (__bf16)a.x; o[1] = (__bf16)a.y; o[2] = (__bf16)a.z; o[3] = (__bf16)a.w;
  o[4] = (__bf16)b.x; o[5] = (__bf16)b.y; o[6] = (__bf16)b.z; o[7] = (__bf16)b.w;
  reinterpret_cast<bf8_t*>(xb)[idx] = o;
}

// ---------------------------------------------------------------------------
// weight fp32 [k][n] -> bf16 [n][k] (transpose), 64x64 tiles, 6 weights
// ---------------------------------------------------------------------------
__global__ __launch_bounds__(256)
void cvt_w_kernel(const float* __restrict__ w0, const float* __restrict__ w1,
                  const float* __restrict__ w2, const float* __restrict__ w3,
                  const float* __restrict__ w4, const float* __restrict__ w5,
                  __bf16* __restrict__ wt)
{
  const int z = blockIdx.z;
  const float* W = (z == 0) ? w0 : (z == 1) ? w1 : (z == 2) ? w2
                 : (z == 3) ? w3 : (z == 4) ? w4 : w5;
  const int n0 = blockIdx.x * 64, k0 = blockIdx.y * 64;
  __shared__ __bf16 Ts[64][72];
  const int tid = threadIdx.x;
  #pragma unroll
  for (int i = 0; i < 4; i++) {
    int p = tid + 256 * i;            // 1024 float4 chunks: 64 k-rows x 16
    int row = p >> 4, c4 = p & 15;
    float4 v = *reinterpret_cast<const float4*>(W + (size_t)(k0 + row) * 1024 + n0 + c4 * 4);
    Ts[c4 * 4 + 0][row] = (__bf16)v.x;
    Ts[c4 * 4 + 1][row] = (__bf16)v.y;
    Ts[c4 * 4 + 2][row] = (__bf16)v.z;
    Ts[c4 * 4 + 3][row] = (__bf16)v.w;
  }
  __syncthreads();
  #pragma unroll
  for (int i = 0; i < 2; i++) {
    int p = tid + 256 * i;            // 512 bf8 chunks: 64 n-rows x 8
    int n = p >> 3, kq = p & 7;
    bf8_t o = *reinterpret_cast<const bf8_t*>(&Ts[n][kq * 8]);
    *reinterpret_cast<bf8_t*>(wt + (size_t)z * 1024 * 1024 + (size_t)(n0 + n) * 1024 + k0 + kq * 8) = o;
  }
}

// ---------------------------------------------------------------------------
// m97-style GEMM: C[8192 x 1024] = A[8192 x 1024] * Bt[z][n][k]^T
// ---------------------------------------------------------------------------
template<bool OUT_BF16>
__global__ __launch_bounds__(256)
void gemm_bt_kernel(const __bf16* __restrict__ A, const __bf16* __restrict__ BtB,
                    void* __restrict__ Cp)
{
  using namespace abc;
  constexpr int K = 1024;
  const int z = blockIdx.z;
  const __bf16* Bt = BtB + (size_t)z * K * 1024;
  const int n0 = blockIdx.x * 128;
  const int m0 = blockIdx.y * 128;
  __shared__ __bf16 As[128 * 64];   // [m][k], unpadded (global_load_lds layout)
  __shared__ __bf16 Bs[128 * 64];   // [n][k]
  const int tid = threadIdx.x;
  const int lane = tid & 63, wvid = tid >> 6;
  const int wr = wvid >> 1, wc = wvid & 1;
  const int quad = lane >> 4, l16 = lane & 15;
  const f4_t fzero = {0.f, 0.f, 0.f, 0.f};
  f4_t acc[4][4];
  #pragma unroll
  for (int i = 0; i < 4; i++)
    #pragma unroll
    for (int j = 0; j < 4; j++) acc[i][j] = fzero;

  const int chunk_row = tid >> 3;
  const int chunk_col = tid & 7;
  for (int k0 = 0; k0 < K; k0 += 64) {
    __syncthreads();
    #pragma unroll
    for (int i = 0; i < 4; i++) {
      glds16(A + (size_t)(m0 + i * 32 + chunk_row) * K + k0 + chunk_col * 8,
             &As[(size_t)(i * 256 + wvid * 64) * 8]);
    }
    #pragma unroll
    for (int i = 0; i < 4; i++) {
      glds16(Bt + (size_t)(n0 + i * 32 + chunk_row) * K + k0 + chunk_col * 8,
             &Bs[(size_t)(i * 256 + wvid * 64) * 8]);
    }
    __syncthreads();
    #pragma unroll
    for (int ks = 0; ks < 2; ks++) {
      bf8_t af[4], bfv[4];
      #pragma unroll
      for (int i = 0; i < 4; i++)
        af[i] = *reinterpret_cast<const bf8_t*>(
            &As[(size_t)(wr * 64 + i * 16 + l16) * 64 + ks * 32 + quad * 8]);
      #pragma unroll
      for (int j = 0; j < 4; j++)
        bfv[j] = *reinterpret_cast<const bf8_t*>(
            &Bs[(size_t)(wc * 64 + j * 16 + l16) * 64 + ks * 32 + quad * 8]);
      #pragma unroll
      for (int i = 0; i < 4; i++)
        #pragma unroll
        for (int j = 0; j < 4; j++)
          acc[i][j] = mfma16(af[i], bfv[j], acc[i][j]);
    }
  }
  const int crow = m0 + wr * 64, ccol = n0 + wc * 64;
  if (OUT_BF16) {
    __bf16* C = (__bf16*)Cp + (size_t)z * BT * 1024;
    #pragma unroll
    for (int i = 0; i < 4; i++)
      #pragma unroll
      for (int j = 0; j < 4; j++)
        #pragma unroll
        for (int r = 0; r < 4; r++)
          C[(size_t)(crow + i * 16 + quad * 4 + r) * 1024 + ccol + j * 16 + l16] =
              (__bf16)acc[i][j][r];
  } else {
    float* C = (float*)Cp;
    #pragma unroll
    for (int i = 0; i < 4; i++)
      #pragma unroll
      for (int j = 0; j < 4; j++)
        #pragma unroll
        for (int r = 0; r < 4; r++)
          C[(size_t)(crow + i * 16 + quad * 4 + r) * 1024 + ccol + j * 16 + l16] =
              acc[i][j][r];
  }
}

// ---------------------------------------------------------------------------
// sg projection
// ---------------------------------------------------------------------------
__global__ __launch_bounds__(256)
void sg_kernel(const float* __restrict__ x, const float* __restrict__ sgw,
               float* __restrict__ sgl)
{
  using namespace abc;
  const int wvid = threadIdx.x >> 6, lane = threadIdx.x & 63;
  const int bt = blockIdx.x * 4 + wvid;
  const float* xr = x + (size_t)bt * 1024;
  float a0 = 0, a1 = 0, a2 = 0, a3 = 0;
  #pragma unroll 4
  for (int u = 0; u < 16; u++) {
    int i = u * 64 + lane;
    float xv = xr[i];
    float4 w = *reinterpret_cast<const float4*>(sgw + (size_t)i * 4);
    a0 += xv * w.x; a1 += xv * w.y; a2 += xv * w.z; a3 += xv * w.w;
  }
  #pragma unroll
  for (int off = 32; off > 0; off >>= 1) {
    a0 += __shfl_down(a0, off);
    a1 += __shfl_down(a1, off);
    a2 += __shfl_down(a2, off);
    a3 += __shfl_down(a3, off);
  }
  if (lane == 0) {
    const int b = bt >> 11, t = bt & (T - 1);
    float r[4] = {a0, a1, a2, a3};
    #pragma unroll
    for (int h = 0; h < 4; h++) {
      float v = r[h];
      float ls = fminf(v, 0.f) - log1pf(expf(-fabsf(v)));
      sgl[(size_t)(b * 4 + h) * T + t] = ls * (1.0f / GN);
    }
  }
}

// ---------------------------------------------------------------------------
// inclusive cumsum over T per (b,h)
// ---------------------------------------------------------------------------
__global__ __launch_bounds__(256)
void scan_kernel(const float* __restrict__ sgl, float* __restrict__ sgc)
{
  using namespace abc;
  const int bh = blockIdx.x;
  const float* in = sgl + (size_t)bh * T;
  float* out = sgc + (size_t)bh * T;
  __shared__ float part[256];
  const int tid = threadIdx.x;
  float v[8]; float s = 0.f;
  #pragma unroll
  for (int i = 0; i < 8; i++) { v[i] = in[tid * 8 + i]; s += v[i]; }
  part[tid] = s;
  __syncthreads();
  for (int off = 1; off < 256; off <<= 1) {
    float a = (tid >= off) ? part[tid - off] : 0.f;
    __syncthreads();
    part[tid] += a;
    __syncthreads();
  }
  float run = (tid > 0) ? part[tid - 1] : 0.f;
  #pragma unroll
  for (int i = 0; i < 8; i++) { run += v[i]; out[tid * 8 + i] = run; }
}

// ---------------------------------------------------------------------------
// prep: RoPE(q), RoPE(k)*exp(cumsum sg), s -> exp(clamp(s)) ; in-place on bf16
// ---------------------------------------------------------------------------
__global__ __launch_bounds__(256)
void prep_kernel(__bf16* __restrict__ q, __bf16* __restrict__ k,
                 __bf16* __restrict__ s, const float* __restrict__ sgc)
{
  using namespace abc;
  const int bt = blockIdx.x;
  const int b = bt >> 11, t = bt & (T - 1);
  const int tid = threadIdx.x;
  const size_t ro = (size_t)bt * 1024;
  #pragma unroll
  for (int i = 0; i < 2; i++) {
    int p = tid + 256 * i;          // 0..511 : h = p/128, d = p%128
    int h = p >> 7, d = p & 127;
    float inv = expf(-(float)d * (9.210340371976184f / 128.0f)); // 10000^(-d/128)
    float ang = (float)t * inv;
    float sn, cs;
    sincosf(ang, &sn, &cs);
    size_t base = ro + (size_t)h * 256 + d;
    float q1 = (float)q[base], q2 = (float)q[base + 128];
    q[base]       = (__bf16)(q1 * cs - q2 * sn);
    q[base + 128] = (__bf16)(q2 * cs + q1 * sn);
    float dec = expf(sgc[(size_t)(b * 4 + h) * T + t]);
    float k1 = (float)k[base], k2 = (float)k[base + 128];
    k[base]       = (__bf16)((k1 * cs - k2 * sn) * dec);
    k[base + 128] = (__bf16)((k2 * cs + k1 * sn) * dec);
  }
  #pragma unroll
  for (int i = 0; i < 4; i++) {
    int e = tid + 256 * i;
    float v = (float)s[ro + e];
    v = fminf(fmaxf(v, -32.f), 32.f);
    s[ro + e] = (__bf16)expf(v);
  }
}

// ---------------------------------------------------------------------------
// transpose chunks: [t=64][f=256] -> [bh][c][f=256][t=64]; up to 2 srcs per
// launch (blockIdx.z). LDS XOR-swizzled: (f,t) at f*64 + ((t>>3)^((f>>3)&7))*8
// + (t&7): write-phase ~4-way conflicts, read = clean b128.
// ---------------------------------------------------------------------------
__global__ __launch_bounds__(256)
void transpose_kernel(const __bf16* __restrict__ s0, const __bf16* __restrict__ s1,
                      __bf16* __restrict__ d0, __bf16* __restrict__ d1)
{
  using namespace abc;
  const int c = blockIdx.x, bh = blockIdx.y, z = blockIdx.z;
  const int b = bh >> 2, h = bh & 3;
  const size_t R = (size_t)b * T + (size_t)c * CH;
  const int F = h * 256;
  const __bf16* src = z ? s1 : s0;
  __bf16* dst = (z ? d1 : d0) + ((size_t)bh * NC + c) * (256 * 64);
  __shared__ __bf16 L[256 * 64];
  const int tid = threadIdx.x;
  #pragma unroll
  for (int j = 0; j < 8; j++) {
    int p = tid + 256 * j;            // (t = p>>5, fc = p&31)
    int t = p >> 5, fc = p & 31;
    bf8_t v = *reinterpret_cast<const bf8_t*>(src + (R + t) * 1024 + F + fc * 8);
    const int sw = ((t >> 3) ^ (fc & 7)) * 8 + (t & 7);
    #pragma unroll
    for (int u = 0; u < 8; u++)
      L[(fc * 8 + u) * 64 + sw] = v[u];
  }
  __syncthreads();
  #pragma unroll
  for (int j = 0; j < 8; j++) {
    int p = tid + 256 * j;            // (f = p>>3, q = p&7)
    int f = p >> 3, q = p & 7;
    int phys = q ^ ((f >> 3) & 7);
    bf8_t o = *reinterpret_cast<const bf8_t*>(&L[f * 64 + phys * 8]);
    *reinterpret_cast<bf8_t*>(dst + (size_t)f * 64 + q * 8) = o;
  }
}

// ---------------------------------------------------------------------------
// per-chunk states (no LDS; fragments straight from global KT/VT/AT):
//   HKc[bh][c][m][k] = sum_t A[t][m] K[t][k]   (part 0/1: m-halves)
//   HVc[bh][c][v][m] = sum_t V[t][v] A[t][m]   (part 2/3: v-halves)
//   csA[bh][c][m]    = sum_t A[t][m]           (part 2)
// ---------------------------------------------------------------------------
__global__ __launch_bounds__(256)
void chunkstate_kernel(const __bf16* __restrict__ KT, const __bf16* __restrict__ VT,
                       const __bf16* __restrict__ AT,
                       __bf16* __restrict__ HKc, __bf16* __restrict__ HVc,
                       float* __restrict__ csA)
{
  using namespace abc;
  const int c = blockIdx.x, bh = blockIdx.y, part = blockIdx.z;
  const size_t TB = ((size_t)bh * NC + c) * (256 * 64);
  const bool isHV = part >= 2;
  const int p2 = part & 1;
  const __bf16* Aop = (isHV ? VT : AT) + TB;   // rows = out-dim (v or m)
  const __bf16* Bop = (isHV ? AT : KT) + TB;   // rows = out-col  (m or k)
  const int tid = threadIdx.x;
  if (part == 2) {
    float ssum = 0.f;
    #pragma unroll
    for (int u = 0; u < 8; u++) {
      bf8_t v = *reinterpret_cast<const bf8_t*>(AT + TB + (size_t)tid * 64 + u * 8);
      #pragma unroll
      for (int w = 0; w < 8; w++) ssum += (float)v[w];
    }
    csA[((size_t)bh * NC + c) * 256 + tid] = ssum;
  }
  const int lane = tid & 63, wvid = tid >> 6;
  const int quad = lane >> 4, l16 = lane & 15;
  const int row0 = p2 * 128 + wvid * 32;
  const f4_t fzero = {0.f, 0.f, 0.f, 0.f};
  f4_t acc[2][16];
  #pragma unroll
  for (int a = 0; a < 2; a++)
    #pragma unroll
    for (int ct = 0; ct < 16; ct++) acc[a][ct] = fzero;
  #pragma unroll
  for (int ks = 0; ks < 2; ks++) {
    bf8_t af0 = *reinterpret_cast<const bf8_t*>(Aop + (size_t)(row0 + l16) * 64 + ks * 32 + quad * 8);
    bf8_t af1 = *reinterpret_cast<const bf8_t*>(Aop + (size_t)(row0 + 16 + l16) * 64 + ks * 32 + quad * 8);
    #pragma unroll
    for (int ct = 0; ct < 16; ct++) {
      bf8_t bv = *reinterpret_cast<const bf8_t*>(Bop + (size_t)(ct * 16 + l16) * 64 + ks * 32 + quad * 8);
      acc[0][ct] = mfma16(af0, bv, acc[0][ct]);
      acc[1][ct] = mfma16(af1, bv, acc[1][ct]);
    }
  }
  __bf16* out = (isHV ? HVc : HKc) + ((size_t)bh * NC + c) * 65536;
  #pragma unroll
  for (int rt = 0; rt < 2; rt++)
    #pragma unroll
    for (int ct = 0; ct < 16; ct++)
      #pragma unroll
      for (int r = 0; r < 4; r++)
        out[(size_t)(row0 + rt * 16 + quad * 4 + r) * 256 + ct * 16 + l16] =
            (__bf16)acc[rt][ct][r];
}

// ---------------------------------------------------------------------------
// in-place exclusive prefix over chunk axis of HKc/HVc (bf16, fp32 run)
// ---------------------------------------------------------------------------
__global__ __launch_bounds__(256)
void prefix_state_kernel(__bf16* __restrict__ HKc, __bf16* __restrict__ HVc)
{
  using namespace abc;
  const int bh = blockIdx.y;
  __bf16* base = (blockIdx.z ? HVc : HKc) + (size_t)bh * NC * 65536;
  const int e = (blockIdx.x * 256 + threadIdx.x) * 4;
  float run0 = 0, run1 = 0, run2 = 0, run3 = 0;
  for (int c = 0; c < NC; c++) {
    __bf16* p = base + (size_t)c * 65536 + e;
    bf4_t v = *reinterpret_cast<const bf4_t*>(p);
    bf4_t o;
    o[0] = (__bf16)run0; o[1] = (__bf16)run1; o[2] = (__bf16)run2; o[3] = (__bf16)run3;
    run0 += (float)v[0]; run1 += (float)v[1]; run2 += (float)v[2]; run3 += (float)v[3];
    *reinterpret_cast<bf4_t*>(p) = o;
  }
}

__global__ __launch_bounds__(256)
void prefix_csa_kernel(float* __restrict__ csA)
{
  using namespace abc;
  const int bh = blockIdx.x, m = threadIdx.x;
  float run = 0.f;
  for (int c = 0; c < NC; c++) {
    float* p = csA + ((size_t)bh * NC + c) * 256 + m;
    float v = *p; *p = run; run += v;
  }
}

// ---------------------------------------------------------------------------
// main chunked ABC attention + fused RMSNorm/SiLU-gate epilogue
// one block per (chunk, bh); each wave owns a 16-row strip; LDS ~45 KB.
// ---------------------------------------------------------------------------
__global__ __launch_bounds__(256)
void attn_kernel(const __bf16* __restrict__ qg, const __bf16* __restrict__ kg,
                 const __bf16* __restrict__ ag, const __bf16* __restrict__ gg,
                 const __bf16* __restrict__ ATp, const __bf16* __restrict__ VTp,
                 const __bf16* __restrict__ HKp, const __bf16* __restrict__ HVp,
                 const float* __restrict__ Zp, const float* __restrict__ gnw,
                 __bf16* __restrict__ yout)
{
  using namespace abc;
  const int c = blockIdx.x, bh = blockIdx.y;
  const int b = bh >> 2, h = bh & 3;
  const size_t R = (size_t)b * T + (size_t)c * CH;
  const int F = h * 256;
  const int tid = threadIdx.x;
  const int lane = tid & 63, wvid = tid >> 6;
  const int quad = lane >> 4, l16 = lane & 15;

  __shared__ __bf16 Ws[64][264];   // W = qv / SumA (per-wave strip)
  __shared__ __bf16 S1s[64][72];   // masked QK^T, later masked P (per-wave strip)
  __shared__ float zs[256];
  __shared__ float gns[256];

  zs[tid] = Zp[((size_t)bh * NC + c) * 256 + tid];
  gns[tid] = gnw[tid];
  __syncthreads();   // only barrier: zs/gns shared across waves

  const f4_t fzero = {0.f, 0.f, 0.f, 0.f};
  const __bf16* qrow = qg + (R + wvid * 16 + l16) * 1024 + F;

  // phase A: S1 = Q K^T (intra-chunk), frags straight from global
  f4_t s1a[4];
  #pragma unroll
  for (int it = 0; it < 4; it++) s1a[it] = fzero;
  #pragma unroll
  for (int ks = 0; ks < 8; ks++) {
    bf8_t aq = *reinterpret_cast<const bf8_t*>(qrow + ks * 32 + quad * 8);
    #pragma unroll
    for (int it = 0; it < 4; it++) {
      bf8_t bk = *reinterpret_cast<const bf8_t*>(
          kg + (R + it * 16 + l16) * 1024 + F + ks * 32 + quad * 8);
      s1a[it] = mfma16(aq, bk, s1a[it]);
    }
  }
  #pragma unroll
  for (int it = 0; it < 4; it++)
    #pragma unroll
    for (int r = 0; r < 4; r++) {
      int tl = wvid * 16 + quad * 4 + r;
      int il = it * 16 + l16;
      S1s[tl][il] = (il <= tl) ? (__bf16)s1a[it][r] : (__bf16)0.0f;
    }

  // phase B: intra numerator (S1_masked @ A) and cumA (L @ A); A^T from global
  const __bf16* atb = ATp + ((size_t)bh * NC + c) * (256 * 64);
  f4_t aok[16], acum[16];
  #pragma unroll
  for (int mt = 0; mt < 16; mt++) { aok[mt] = fzero; acum[mt] = fzero; }
  #pragma unroll
  for (int iks = 0; iks < 2; iks++) {
    bf8_t s1f = *reinterpret_cast<const bf8_t*>(&S1s[wvid * 16 + l16][iks * 32 + quad * 8]);
    bf8_t lf;                        // lower-tri ones, built in registers
    #pragma unroll
    for (int j = 0; j < 8; j++)
      lf[j] = (iks * 32 + quad * 8 + j <= wvid * 16 + l16) ? (__bf16)1.0f : (__bf16)0.0f;
    #pragma unroll
    for (int mt = 0; mt < 16; mt++) {
      bf8_t bfa = *reinterpret_cast<const bf8_t*>(
          atb + (size_t)(mt * 16 + l16) * 64 + iks * 32 + quad * 8);
      aok[mt]  = mfma16(s1f, bfa, aok[mt]);
      acum[mt] = mfma16(lf,  bfa, acum[mt]);
    }
  }
  // phase C: cross numerator  Q @ HKpre
  const __bf16* hkb = HKp + ((size_t)bh * NC + c) * 65536;
  #pragma unroll
  for (int ks = 0; ks < 8; ks++) {
    bf8_t aq = *reinterpret_cast<const bf8_t*>(qrow + ks * 32 + quad * 8);
    #pragma unroll
    for (int mt = 0; mt < 16; mt++) {
      bf8_t bv = *reinterpret_cast<const bf8_t*>(
          hkb + (size_t)(mt * 16 + l16) * 256 + ks * 32 + quad * 8);
      aok[mt] = mfma16(aq, bv, aok[mt]);
    }
  }
  // softmax over m ; W = qv / SumA  (16-lane quad-group reductions)
  #pragma unroll
  for (int r = 0; r < 4; r++) {
    float ovv[16], sa[16];
    float mx = -3.0e38f;
    #pragma unroll
    for (int mt = 0; mt < 16; mt++) {
      sa[mt] = zs[mt * 16 + l16] + acum[mt][r];
      ovv[mt] = SCALE * aok[mt][r] / sa[mt];
      mx = fmaxf(mx, ovv[mt]);
    }
    #pragma unroll
    for (int off = 1; off < 16; off <<= 1) mx = fmaxf(mx, __shfl_xor(mx, off));
    float se = 0.f;
    #pragma unroll
    for (int mt = 0; mt < 16; mt++) { ovv[mt] = __expf(ovv[mt] - mx); se += ovv[mt]; }
    #pragma unroll
    for (int off = 1; off < 16; off <<= 1) se += __shfl_xor(se, off);
    float inv = 1.0f / se;
    int tl = wvid * 16 + quad * 4 + r;
    #pragma unroll
    for (int mt = 0; mt < 16; mt++)
      Ws[tl][mt * 16 + l16] = (__bf16)(ovv[mt] * inv / sa[mt]);
  }

  // phase 4a: P = mask(W @ A^T); B-op = A natural rows from global
  f4_t pacc[4];
  #pragma unroll
  for (int it = 0; it < 4; it++) pacc[it] = fzero;
  #pragma unroll
  for (int ks = 0; ks < 8; ks++) {
    bf8_t wf = *reinterpret_cast<const bf8_t*>(&Ws[wvid * 16 + l16][ks * 32 + quad * 8]);
    #pragma unroll
    for (int it = 0; it < 4; it++) {
      bf8_t ba = *reinterpret_cast<const bf8_t*>(
          ag + (R + it * 16 + l16) * 1024 + F + ks * 32 + quad * 8);
      pacc[it] = mfma16(wf, ba, pacc[it]);
    }
  }
  #pragma unroll
  for (int it = 0; it < 4; it++)
    #pragma unroll
    for (int r = 0; r < 4; r++) {
      int tl = wvid * 16 + quad * 4 + r;
      int il = it * 16 + l16;
      S1s[tl][il] = (il <= tl) ? (__bf16)pacc[it][r] : (__bf16)0.0f;
    }

  // phase 4b: O = W @ HVpre^T + P @ V  (V^T natural rows from global)
  f4_t oacc[16];
  #pragma unroll
  for (int vt = 0; vt < 16; vt++) oacc[vt] = fzero;
  const __bf16* hvb = HVp + ((size_t)bh * NC + c) * 65536;
  #pragma unroll
  for (int ks = 0; ks < 8; ks++) {
    bf8_t wf = *reinterpret_cast<const bf8_t*>(&Ws[wvid * 16 + l16][ks * 32 + quad * 8]);
    #pragma unroll
    for (int vt = 0; vt < 16; vt++) {
      bf8_t bv = *reinterpret_cast<const bf8_t*>(
          hvb + (size_t)(vt * 16 + l16) * 256 + ks * 32 + quad * 8);
      oacc[vt] = mfma16(wf, bv, oacc[vt]);
    }
  }
  const __bf16* vtb = VTp + ((size_t)bh * NC + c) * (256 * 64);
  #pragma unroll
  for (int iks = 0; iks < 2; iks++) {
    bf8_t pf = *reinterpret_cast<const bf8_t*>(&S1s[wvid * 16 + l16][iks * 32 + quad * 8]);
    #pragma unroll
    for (int vt = 0; vt < 16; vt++) {
      bf8_t bvt = *reinterpret_cast<const bf8_t*>(
          vtb + (size_t)(vt * 16 + l16) * 64 + iks * 32 + quad * 8);
      oacc[vt] = mfma16(pf, bvt, oacc[vt]);
    }
  }
  // epilogue: fused RMSNorm * gn_w * g * sigmoid(g) -> y (bf16)
  #pragma unroll
  for (int r = 0; r < 4; r++) {
    float ss = 0.f;
    #pragma unroll
    for (int vt = 0; vt < 16; vt++) ss += oacc[vt][r] * oacc[vt][r];
    #pragma unroll
    for (int off = 1; off < 16; off <<= 1) ss += __shfl_xor(ss, off);
    float rinv = rsqrtf(ss * (1.0f / 256.0f) + EPS);
    int tl = wvid * 16 + quad * 4 + r;
    const __bf16* grow = gg + (R + tl) * 1024 + F;
    __bf16* yrow = yout + (R + tl) * 1024 + F;
    #pragma unroll
    for (int vt = 0; vt < 16; vt++) {
      int v = vt * 16 + l16;
      float gvl = (float)grow[v];
      float yv = oacc[vt][r] * rinv * gns[v] * gvl / (1.0f + __expf(-gvl));
      yrow[v] = (__bf16)yv;
    }
  }
}

// ---------------------------------------------------------------------------
// Workspace layout (MB), peak 253 MB (same high-water mark as passing R3):
//   0-16 q | 16-32 k | 32-48 v -> AT | 48-64 g | 64-80 a | 80-96 xb -> VT
//   96-97 sgl/sgc/csA | 97-161 HKc | 161-225 HVc | 225-237 wt
//   237-253 KT -> y_bf
// Overlay safety (stream-ordered): xb dead after proj gemm, before transpose1
// writes VT. v dead after transpose1 reads it; transpose2 then writes AT
// there. KT dead after chunkstate; attn then writes y there.
// ---------------------------------------------------------------------------
extern "C" void kernel_launch(void* const* d_in, const int* in_sizes, int n_in,
                              void* d_out, int out_size, void* d_ws, size_t ws_size,
                              hipStream_t stream) {
  using namespace abc;
  (void)in_sizes; (void)n_in; (void)out_size; (void)ws_size;
  const float* x    = (const float*)d_in[0];
  const float* q_w  = (const float*)d_in[1];
  const float* k_w  = (const float*)d_in[2];
  const float* v_w  = (const float*)d_in[3];
  const float* g_w  = (const float*)d_in[4];
  const float* s_w  = (const float*)d_in[5];
  const float* sg_w = (const float*)d_in[6];
  const float* gn_w = (const float*)d_in[7];
  const float* o_w  = (const float*)d_in[8];
  float* out = (float*)d_out;

  char* ws = (char*)d_ws;
  const size_t PROJ = (size_t)BT * 1024;       // elements per projection
  __bf16* proj = (__bf16*)ws;
  __bf16* q_bf = proj + 0 * PROJ;
  __bf16* k_bf = proj + 1 * PROJ;
  __bf16* v_bf = proj + 2 * PROJ;              // -> AT after transpose1
  __bf16* g_bf = proj + 3 * PROJ;
  __bf16* a_bf = proj + 4 * PROJ;
  __bf16* xb   = proj + 5 * PROJ;              // -> VT after proj gemm
  float* sgl = (float*)(ws + (size_t)96 * 1024 * 1024);
  float* sgc = sgl + (size_t)BH * T;
  float* csA = sgc + (size_t)BH * T;           // 16*32*256 floats
  __bf16* HKc = (__bf16*)(ws + (size_t)97 * 1024 * 1024);   // 64MB
  __bf16* HVc = HKc + (size_t)BH * NC * 65536;               // 64MB
  __bf16* wt  = (__bf16*)(ws + (size_t)225 * 1024 * 1024);  // 12MB
  __bf16* KT  = (__bf16*)(ws + (size_t)237 * 1024 * 1024);  // 16MB
  __bf16* VT  = xb;                            // overlay (xb dead)
  __bf16* AT  = v_bf;                          // overlay (v dead)
  __bf16* y_bf = KT;                           // overlay (KT dead)

  dim3 blk(256);
  cvt_w_kernel<<<dim3(16, 16, 6), blk, 0, stream>>>(q_w, k_w, v_w, g_w, s_w, o_w, wt);
  cvt_x_kernel<<<dim3(BT * 1024 / (256 * 8)), blk, 0, stream>>>(x, xb);
  gemm_bt_kernel<true><<<dim3(8, 64, 5), blk, 0, stream>>>(xb, wt, proj);
  sg_kernel<<<dim3(BT / 4), blk, 0, stream>>>(x, sg_w, sgl);
  scan_kernel<<<dim3(BH), blk, 0, stream>>>(sgl, sgc);
  prep_kernel<<<dim3(BT), blk, 0, stream>>>(q_bf, k_bf, a_bf, sgc);
  transpose_kernel<<<dim3(NC, BH, 2), blk, 0, stream>>>(k_bf, v_bf, KT, VT);
  transpose_kernel<<<dim3(NC, BH, 1), blk, 0, stream>>>(a_bf, a_bf, AT, AT);
  chunkstate_kernel<<<dim3(NC, BH, 4), blk, 0, stream>>>(KT, VT, AT, HKc, HVc, csA);
  prefix_state_kernel<<<dim3(64, BH, 2), blk, 0, stream>>>(HKc, HVc);
  prefix_csa_kernel<<<dim3(BH), blk, 0, stream>>>(csA);
  attn_kernel<<<dim3(NC, BH), blk, 0, stream>>>(
      q_bf, k_bf, a_bf, g_bf, AT, VT, HKc, HVc, csA, gn_w, y_bf);
  gemm_bt_kernel<false><<<dim3(8, 64, 1), blk, 0, stream>>>(
      y_bf, wt + (size_t)5 * 1024 * 1024, out);
}

// Round 6
// 502.327 us; speedup vs baseline: 1.8744x; 1.1323x over previous
//
#include <hip/hip_runtime.h>
#include <hip/hip_bf16.h>
#include <stdint.h>
#include <stddef.h>
#include <math.h>

typedef __bf16 bf8_t __attribute__((ext_vector_type(8)));
typedef __bf16 bf4_t __attribute__((ext_vector_type(4)));
typedef float  f4_t  __attribute__((ext_vector_type(4)));
typedef unsigned int u32;

#define DEV static __device__ __forceinline__

namespace abc {
constexpr int B = 4, T = 2048, D = 1024, H = 4;
constexpr int BT = B * T;          // 8192
constexpr int CH = 64;             // chunk length
constexpr int NC = T / CH;         // 32 chunks
constexpr int BH = B * H;          // 16
constexpr float SCALE = 0.0625f;   // DK^-0.5
constexpr float GN = 16.0f;
constexpr float EPS = 1e-5f;
}

DEV f4_t mfma16(bf8_t a, bf8_t b, f4_t c) {
  return __builtin_amdgcn_mfma_f32_16x16x32_bf16(a, b, c, 0, 0, 0);
}

// async global->LDS, 16B per lane; lds dest must be wave-uniform base (+lane*16)
DEV void glds16(const void* g, void* l) {
  __builtin_amdgcn_global_load_lds(
      (const __attribute__((address_space(1))) u32*)g,
      (__attribute__((address_space(3))) u32*)l, 16, 0, 0);
}

// stage a ROWSx32col bf16 slice into LDS, group-XOR-swizzled on the GLOBAL
// gather side: LDS 16B-group p holds global (row m=p>>2, colgrp (p&3)^(m&3)).
template<int ROWS>
DEV void stage(const __bf16* __restrict__ g, int S /*elem row stride*/,
               __bf16* lds, int tid) {
  #pragma unroll
  for (int i = 0; i < ROWS / 64; i++) {
    int p = i * 256 + tid;
    int m = p >> 2;
    int q = (p & 3) ^ (m & 3);
    glds16(g + (size_t)m * S + q * 8, lds + (i * 256 + (tid & ~63)) * 8);
  }
}
// read B-fragment (row m, k-group quad) from a staged slice
DEV bf8_t bfrag(const __bf16* sl, int m, int quad) {
  return *reinterpret_cast<const bf8_t*>(sl + m * 32 + ((quad ^ (m & 3)) << 3));
}

// ---------------------------------------------------------------------------
// x fp32 -> bf16 (row-major unchanged). 8 elems/thread.
// ---------------------------------------------------------------------------
__global__ __launch_bounds__(256)
void cvt_x_kernel(const float* __restrict__ x, __bf16* __restrict__ xb)
{
  const int idx = blockIdx.x * 256 + threadIdx.x;   // 1M threads total
  const float4* src = reinterpret_cast<const float4*>(x);
  float4 a = src[(size_t)idx * 2];
  float4 b = src[(size_t)idx * 2 + 1];
  bf8_t o;
  o[0] = (__bf16)a.x; o[1] = (__bf16)a.y; o[2] = (__bf16)a.z; o[3] = (__bf16)a.w;
  o[4] = (__bf16)b.x; o[5] = (__bf16)b.y; o[6] = (__bf16)b.z; o[7] = (__bf16)b.w;
  reinterpret_cast<bf8_t*>(xb)[idx] = o;
}

// ---------------------------------------------------------------------------
// weight fp32 [k][n] -> bf16 [n][k] (transpose), 64x64 tiles, 6 weights
// ---------------------------------------------------------------------------
__global__ __launch_bounds__(256)
void cvt_w_kernel(const float* __restrict__ w0, const float* __restrict__ w1,
                  const float* __restrict__ w2, const float* __restrict__ w3,
                  const float* __restrict__ w4, const float* __restrict__ w5,
                  __bf16* __restrict__ wt)
{
  const int z = blockIdx.z;
  const float* W = (z == 0) ? w0 : (z == 1) ? w1 : (z == 2) ? w2
                 : (z == 3) ? w3 : (z == 4) ? w4 : w5;
  const int n0 = blockIdx.x * 64, k0 = blockIdx.y * 64;
  __shared__ __bf16 Ts[64][72];
  const int tid = threadIdx.x;
  #pragma unroll
  for (int i = 0; i < 4; i++) {
    int p = tid + 256 * i;            // 1024 float4 chunks: 64 k-rows x 16
    int row = p >> 4, c4 = p & 15;
    float4 v = *reinterpret_cast<const float4*>(W + (size_t)(k0 + row) * 1024 + n0 + c4 * 4);
    Ts[c4 * 4 + 0][row] = (__bf16)v.x;
    Ts[c4 * 4 + 1][row] = (__bf16)v.y;
    Ts[c4 * 4 + 2][row] = (__bf16)v.z;
    Ts[c4 * 4 + 3][row] = (__bf16)v.w;
  }
  __syncthreads();
  #pragma unroll
  for (int i = 0; i < 2; i++) {
    int p = tid + 256 * i;            // 512 bf8 chunks: 64 n-rows x 8
    int n = p >> 3, kq = p & 7;
    bf8_t o = *reinterpret_cast<const bf8_t*>(&Ts[n][kq * 8]);
    *reinterpret_cast<bf8_t*>(wt + (size_t)z * 1024 * 1024 + (size_t)(n0 + n) * 1024 + k0 + kq * 8) = o;
  }
}

// ---------------------------------------------------------------------------
// m97-style GEMM: C[8192 x 1024] = A[8192 x 1024] * Bt[z][n][k]^T
// ---------------------------------------------------------------------------
template<bool OUT_BF16>
__global__ __launch_bounds__(256)
void gemm_bt_kernel(const __bf16* __restrict__ A, const __bf16* __restrict__ BtB,
                    void* __restrict__ Cp)
{
  using namespace abc;
  constexpr int K = 1024;
  const int z = blockIdx.z;
  const __bf16* Bt = BtB + (size_t)z * K * 1024;
  const int n0 = blockIdx.x * 128;
  const int m0 = blockIdx.y * 128;
  __shared__ __bf16 As[128 * 64];   // [m][k], unpadded (global_load_lds layout)
  __shared__ __bf16 Bs[128 * 64];   // [n][k]
  const int tid = threadIdx.x;
  const int lane = tid & 63, wvid = tid >> 6;
  const int wr = wvid >> 1, wc = wvid & 1;
  const int quad = lane >> 4, l16 = lane & 15;
  const f4_t fzero = {0.f, 0.f, 0.f, 0.f};
  f4_t acc[4][4];
  #pragma unroll
  for (int i = 0; i < 4; i++)
    #pragma unroll
    for (int j = 0; j < 4; j++) acc[i][j] = fzero;

  const int chunk_row = tid >> 3;
  const int chunk_col = tid & 7;
  for (int k0 = 0; k0 < K; k0 += 64) {
    __syncthreads();
    #pragma unroll
    for (int i = 0; i < 4; i++) {
      glds16(A + (size_t)(m0 + i * 32 + chunk_row) * K + k0 + chunk_col * 8,
             &As[(size_t)(i * 256 + wvid * 64) * 8]);
    }
    #pragma unroll
    for (int i = 0; i < 4; i++) {
      glds16(Bt + (size_t)(n0 + i * 32 + chunk_row) * K + k0 + chunk_col * 8,
             &Bs[(size_t)(i * 256 + wvid * 64) * 8]);
    }
    __syncthreads();
    #pragma unroll
    for (int ks = 0; ks < 2; ks++) {
      bf8_t af[4], bfv[4];
      #pragma unroll
      for (int i = 0; i < 4; i++)
        af[i] = *reinterpret_cast<const bf8_t*>(
            &As[(size_t)(wr * 64 + i * 16 + l16) * 64 + ks * 32 + quad * 8]);
      #pragma unroll
      for (int j = 0; j < 4; j++)
        bfv[j] = *reinterpret_cast<const bf8_t*>(
            &Bs[(size_t)(wc * 64 + j * 16 + l16) * 64 + ks * 32 + quad * 8]);
      #pragma unroll
      for (int i = 0; i < 4; i++)
        #pragma unroll
        for (int j = 0; j < 4; j++)
          acc[i][j] = mfma16(af[i], bfv[j], acc[i][j]);
    }
  }
  const int crow = m0 + wr * 64, ccol = n0 + wc * 64;
  if (OUT_BF16) {
    __bf16* C = (__bf16*)Cp + (size_t)z * BT * 1024;
    #pragma unroll
    for (int i = 0; i < 4; i++)
      #pragma unroll
      for (int j = 0; j < 4; j++)
        #pragma unroll
        for (int r = 0; r < 4; r++)
          C[(size_t)(crow + i * 16 + quad * 4 + r) * 1024 + ccol + j * 16 + l16] =
              (__bf16)acc[i][j][r];
  } else {
    float* C = (float*)Cp;
    #pragma unroll
    for (int i = 0; i < 4; i++)
      #pragma unroll
      for (int j = 0; j < 4; j++)
        #pragma unroll
        for (int r = 0; r < 4; r++)
          C[(size_t)(crow + i * 16 + quad * 4 + r) * 1024 + ccol + j * 16 + l16] =
              acc[i][j][r];
  }
}

// ---------------------------------------------------------------------------
// sg projection
// ---------------------------------------------------------------------------
__global__ __launch_bounds__(256)
void sg_kernel(const float* __restrict__ x, const float* __restrict__ sgw,
               float* __restrict__ sgl)
{
  using namespace abc;
  const int wvid = threadIdx.x >> 6, lane = threadIdx.x & 63;
  const int bt = blockIdx.x * 4 + wvid;
  const float* xr = x + (size_t)bt * 1024;
  float a0 = 0, a1 = 0, a2 = 0, a3 = 0;
  #pragma unroll 4
  for (int u = 0; u < 16; u++) {
    int i = u * 64 + lane;
    float xv = xr[i];
    float4 w = *reinterpret_cast<const float4*>(sgw + (size_t)i * 4);
    a0 += xv * w.x; a1 += xv * w.y; a2 += xv * w.z; a3 += xv * w.w;
  }
  #pragma unroll
  for (int off = 32; off > 0; off >>= 1) {
    a0 += __shfl_down(a0, off);
    a1 += __shfl_down(a1, off);
    a2 += __shfl_down(a2, off);
    a3 += __shfl_down(a3, off);
  }
  if (lane == 0) {
    const int b = bt >> 11, t = bt & (T - 1);
    float r[4] = {a0, a1, a2, a3};
    #pragma unroll
    for (int h = 0; h < 4; h++) {
      float v = r[h];
      float ls = fminf(v, 0.f) - log1pf(expf(-fabsf(v)));
      sgl[(size_t)(b * 4 + h) * T + t] = ls * (1.0f / GN);
    }
  }
}

// ---------------------------------------------------------------------------
// inclusive cumsum over T per (b,h)
// ---------------------------------------------------------------------------
__global__ __launch_bounds__(256)
void scan_kernel(const float* __restrict__ sgl, float* __restrict__ sgc)
{
  using namespace abc;
  const int bh = blockIdx.x;
  const float* in = sgl + (size_t)bh * T;
  float* out = sgc + (size_t)bh * T;
  __shared__ float part[256];
  const int tid = threadIdx.x;
  float v[8]; float s = 0.f;
  #pragma unroll
  for (int i = 0; i < 8; i++) { v[i] = in[tid * 8 + i]; s += v[i]; }
  part[tid] = s;
  __syncthreads();
  for (int off = 1; off < 256; off <<= 1) {
    float a = (tid >= off) ? part[tid - off] : 0.f;
    __syncthreads();
    part[tid] += a;
    __syncthreads();
  }
  float run = (tid > 0) ? part[tid - 1] : 0.f;
  #pragma unroll
  for (int i = 0; i < 8; i++) { run += v[i]; out[tid * 8 + i] = run; }
}

// ---------------------------------------------------------------------------
// prep: RoPE(q), RoPE(k)*exp(cumsum sg), s -> exp(clamp(s)) ; in-place on bf16
// ---------------------------------------------------------------------------
__global__ __launch_bounds__(256)
void prep_kernel(__bf16* __restrict__ q, __bf16* __restrict__ k,
                 __bf16* __restrict__ s, const float* __restrict__ sgc)
{
  using namespace abc;
  const int bt = blockIdx.x;
  const int b = bt >> 11, t = bt & (T - 1);
  const int tid = threadIdx.x;
  const size_t ro = (size_t)bt * 1024;
  #pragma unroll
  for (int i = 0; i < 2; i++) {
    int p = tid + 256 * i;          // 0..511 : h = p/128, d = p%128
    int h = p >> 7, d = p & 127;
    float inv = expf(-(float)d * (9.210340371976184f / 128.0f)); // 10000^(-d/128)
    float ang = (float)t * inv;
    float sn, cs;
    sincosf(ang, &sn, &cs);
    size_t base = ro + (size_t)h * 256 + d;
    float q1 = (float)q[base], q2 = (float)q[base + 128];
    q[base]       = (__bf16)(q1 * cs - q2 * sn);
    q[base + 128] = (__bf16)(q2 * cs + q1 * sn);
    float dec = expf(sgc[(size_t)(b * 4 + h) * T + t]);
    float k1 = (float)k[base], k2 = (float)k[base + 128];
    k[base]       = (__bf16)((k1 * cs - k2 * sn) * dec);
    k[base + 128] = (__bf16)((k2 * cs + k1 * sn) * dec);
  }
  #pragma unroll
  for (int i = 0; i < 4; i++) {
    int e = tid + 256 * i;
    float v = (float)s[ro + e];
    v = fminf(fmaxf(v, -32.f), 32.f);
    s[ro + e] = (__bf16)expf(v);
  }
}

// ---------------------------------------------------------------------------
// transpose chunks: [t=64][f=256] -> [bh][c][f=256][t=64]; up to 2 srcs per
// launch (blockIdx.z). LDS XOR-swizzled.
// ---------------------------------------------------------------------------
__global__ __launch_bounds__(256)
void transpose_kernel(const __bf16* __restrict__ s0, const __bf16* __restrict__ s1,
                      __bf16* __restrict__ d0, __bf16* __restrict__ d1)
{
  using namespace abc;
  const int c = blockIdx.x, bh = blockIdx.y, z = blockIdx.z;
  const int b = bh >> 2, h = bh & 3;
  const size_t R = (size_t)b * T + (size_t)c * CH;
  const int F = h * 256;
  const __bf16* src = z ? s1 : s0;
  __bf16* dst = (z ? d1 : d0) + ((size_t)bh * NC + c) * (256 * 64);
  __shared__ __bf16 L[256 * 64];
  const int tid = threadIdx.x;
  #pragma unroll
  for (int j = 0; j < 8; j++) {
    int p = tid + 256 * j;            // (t = p>>5, fc = p&31)
    int t = p >> 5, fc = p & 31;
    bf8_t v = *reinterpret_cast<const bf8_t*>(src + (R + t) * 1024 + F + fc * 8);
    const int sw = ((t >> 3) ^ (fc & 7)) * 8 + (t & 7);
    #pragma unroll
    for (int u = 0; u < 8; u++)
      L[(fc * 8 + u) * 64 + sw] = v[u];
  }
  __syncthreads();
  #pragma unroll
  for (int j = 0; j < 8; j++) {
    int p = tid + 256 * j;            // (f = p>>3, q = p&7)
    int f = p >> 3, q = p & 7;
    int phys = q ^ ((f >> 3) & 7);
    bf8_t o = *reinterpret_cast<const bf8_t*>(&L[f * 64 + phys * 8]);
    *reinterpret_cast<bf8_t*>(dst + (size_t)f * 64 + q * 8) = o;
  }
}

// ---------------------------------------------------------------------------
// per-chunk states (no LDS; fragments straight from global KT/VT/AT):
// ---------------------------------------------------------------------------
__global__ __launch_bounds__(256)
void chunkstate_kernel(const __bf16* __restrict__ KT, const __bf16* __restrict__ VT,
                       const __bf16* __restrict__ AT,
                       __bf16* __restrict__ HKc, __bf16* __restrict__ HVc,
                       float* __restrict__ csA)
{
  using namespace abc;
  const int c = blockIdx.x, bh = blockIdx.y, part = blockIdx.z;
  const size_t TB = ((size_t)bh * NC + c) * (256 * 64);
  const bool isHV = part >= 2;
  const int p2 = part & 1;
  const __bf16* Aop = (isHV ? VT : AT) + TB;   // rows = out-dim (v or m)
  const __bf16* Bop = (isHV ? AT : KT) + TB;   // rows = out-col  (m or k)
  const int tid = threadIdx.x;
  if (part == 2) {
    float ssum = 0.f;
    #pragma unroll
    for (int u = 0; u < 8; u++) {
      bf8_t v = *reinterpret_cast<const bf8_t*>(AT + TB + (size_t)tid * 64 + u * 8);
      #pragma unroll
      for (int w = 0; w < 8; w++) ssum += (float)v[w];
    }
    csA[((size_t)bh * NC + c) * 256 + tid] = ssum;
  }
  const int lane = tid & 63, wvid = tid >> 6;
  const int quad = lane >> 4, l16 = lane & 15;
  const int row0 = p2 * 128 + wvid * 32;
  const f4_t fzero = {0.f, 0.f, 0.f, 0.f};
  f4_t acc[2][16];
  #pragma unroll
  for (int a = 0; a < 2; a++)
    #pragma unroll
    for (int ct = 0; ct < 16; ct++) acc[a][ct] = fzero;
  #pragma unroll
  for (int ks = 0; ks < 2; ks++) {
    bf8_t af0 = *reinterpret_cast<const bf8_t*>(Aop + (size_t)(row0 + l16) * 64 + ks * 32 + quad * 8);
    bf8_t af1 = *reinterpret_cast<const bf8_t*>(Aop + (size_t)(row0 + 16 + l16) * 64 + ks * 32 + quad * 8);
    #pragma unroll
    for (int ct = 0; ct < 16; ct++) {
      bf8_t bv = *reinterpret_cast<const bf8_t*>(Bop + (size_t)(ct * 16 + l16) * 64 + ks * 32 + quad * 8);
      acc[0][ct] = mfma16(af0, bv, acc[0][ct]);
      acc[1][ct] = mfma16(af1, bv, acc[1][ct]);
    }
  }
  __bf16* out = (isHV ? HVc : HKc) + ((size_t)bh * NC + c) * 65536;
  #pragma unroll
  for (int rt = 0; rt < 2; rt++)
    #pragma unroll
    for (int ct = 0; ct < 16; ct++)
      #pragma unroll
      for (int r = 0; r < 4; r++)
        out[(size_t)(row0 + rt * 16 + quad * 4 + r) * 256 + ct * 16 + l16] =
            (__bf16)acc[rt][ct][r];
}

// ---------------------------------------------------------------------------
// in-place exclusive prefix over chunk axis of HKc/HVc (bf16, fp32 run)
// ---------------------------------------------------------------------------
__global__ __launch_bounds__(256)
void prefix_state_kernel(__bf16* __restrict__ HKc, __bf16* __restrict__ HVc)
{
  using namespace abc;
  const int bh = blockIdx.y;
  __bf16* base = (blockIdx.z ? HVc : HKc) + (size_t)bh * NC * 65536;
  const int e = (blockIdx.x * 256 + threadIdx.x) * 4;
  float run0 = 0, run1 = 0, run2 = 0, run3 = 0;
  for (int c = 0; c < NC; c++) {
    __bf16* p = base + (size_t)c * 65536 + e;
    bf4_t v = *reinterpret_cast<const bf4_t*>(p);
    bf4_t o;
    o[0] = (__bf16)run0; o[1] = (__bf16)run1; o[2] = (__bf16)run2; o[3] = (__bf16)run3;
    run0 += (float)v[0]; run1 += (float)v[1]; run2 += (float)v[2]; run3 += (float)v[3];
    *reinterpret_cast<bf4_t*>(p) = o;
  }
}

__global__ __launch_bounds__(256)
void prefix_csa_kernel(float* __restrict__ csA)
{
  using namespace abc;
  const int bh = blockIdx.x, m = threadIdx.x;
  float run = 0.f;
  for (int c = 0; c < NC; c++) {
    float* p = csA + ((size_t)bh * NC + c) * 256 + m;
    float v = *p; *p = run; run += v;
  }
}

// ---------------------------------------------------------------------------
// main chunked ABC attention + fused RMSNorm/SiLU-gate epilogue
// one block per (chunk, bh). Shared B-operands (K, AT, HK, A, HV, VT) stream
// through a 2x16KB double-buffered LDS ring via global_load_lds (36 slices,
// group-XOR swizzle folded into the global gather). LDS 76 KB -> 2 blocks/CU.
// ---------------------------------------------------------------------------
__global__ __launch_bounds__(256)
void attn_kernel(const __bf16* __restrict__ qg, const __bf16* __restrict__ kg,
                 const __bf16* __restrict__ ag, const __bf16* __restrict__ gg,
                 const __bf16* __restrict__ ATp, const __bf16* __restrict__ VTp,
                 const __bf16* __restrict__ HKp, const __bf16* __restrict__ HVp,
                 const float* __restrict__ Zp, const float* __restrict__ gnw,
                 __bf16* __restrict__ yout)
{
  using namespace abc;
  const int c = blockIdx.x, bh = blockIdx.y;
  const int b = bh >> 2, h = bh & 3;
  const size_t R = (size_t)b * T + (size_t)c * CH;
  const int F = h * 256;
  const int tid = threadIdx.x;
  const int lane = tid & 63, wvid = tid >> 6;
  const int quad = lane >> 4, l16 = lane & 15;

  __shared__ __bf16 ST[2][8192];   // staging ring, 2 x 16 KB
  __shared__ __bf16 Ws[64][264];   // W = qv / SumA (per-wave strip)
  __shared__ __bf16 S1s[64][72];   // masked QK^T, later masked P (per-wave strip)
  __shared__ float zs[256];
  __shared__ float gns[256];

  const __bf16* atb = ATp + ((size_t)bh * NC + c) * (256 * 64);
  const __bf16* vtb = VTp + ((size_t)bh * NC + c) * (256 * 64);
  const __bf16* hkb = HKp + ((size_t)bh * NC + c) * 65536;
  const __bf16* hvb = HVp + ((size_t)bh * NC + c) * 65536;
  const __bf16* kbase = kg + R * 1024 + F;
  const __bf16* abase = ag + R * 1024 + F;

  zs[tid] = Zp[((size_t)bh * NC + c) * 256 + tid];
  gns[tid] = gnw[tid];

  // preload Q fragments (row = own strip row, all 8 k-groups)
  const __bf16* qrow = qg + (R + wvid * 16 + l16) * 1024 + F;
  bf8_t aq[8];
  #pragma unroll
  for (int ks = 0; ks < 8; ks++)
    aq[ks] = *reinterpret_cast<const bf8_t*>(qrow + ks * 32 + quad * 8);

  const f4_t fzero = {0.f, 0.f, 0.f, 0.f};

  // slice pipeline: s = 0..35 ; buffer = s&1
  stage<64>(kbase, 1024, ST[0], tid);               // slice 0: K ks=0
  __syncthreads();

  // ---- phase A: S1 = Q K^T (8 K-slices, s=0..7) ----
  f4_t s1a[4];
  #pragma unroll
  for (int it = 0; it < 4; it++) s1a[it] = fzero;
  #pragma unroll
  for (int ks = 0; ks < 8; ks++) {
    if (ks < 7) stage<64>(kbase + (ks + 1) * 32, 1024, ST[(ks + 1) & 1], tid);
    else        stage<256>(atb, 64, ST[0], tid);    // slice 8: AT iks=0
    const __bf16* sl = ST[ks & 1];
    #pragma unroll
    for (int it = 0; it < 4; it++) {
      bf8_t bk = bfrag(sl, it * 16 + l16, quad);
      s1a[it] = mfma16(aq[ks], bk, s1a[it]);
    }
    __syncthreads();
  }
  #pragma unroll
  for (int it = 0; it < 4; it++)
    #pragma unroll
    for (int r = 0; r < 4; r++) {
      int tl = wvid * 16 + quad * 4 + r;
      int il = it * 16 + l16;
      S1s[tl][il] = (il <= tl) ? (__bf16)s1a[it][r] : (__bf16)0.0f;
    }

  // ---- phase B: intra numerator + cumA (2 AT-slices, s=8..9) ----
  f4_t aok[16], acum[16];
  #pragma unroll
  for (int mt = 0; mt < 16; mt++) { aok[mt] = fzero; acum[mt] = fzero; }
  #pragma unroll
  for (int iks = 0; iks < 2; iks++) {
    if (iks == 0) stage<256>(atb + 32, 64, ST[1], tid);   // slice 9: AT iks=1
    else          stage<256>(hkb, 256, ST[0], tid);       // slice 10: HK ks=0
    const __bf16* sl = ST[iks & 1];
    bf8_t s1f = *reinterpret_cast<const bf8_t*>(&S1s[wvid * 16 + l16][iks * 32 + quad * 8]);
    bf8_t lf;
    #pragma unroll
    for (int j = 0; j < 8; j++)
      lf[j] = (iks * 32 + quad * 8 + j <= wvid * 16 + l16) ? (__bf16)1.0f : (__bf16)0.0f;
    #pragma unroll
    for (int mt = 0; mt < 16; mt++) {
      bf8_t bfa = bfrag(sl, mt * 16 + l16, quad);
      aok[mt]  = mfma16(s1f, bfa, aok[mt]);
      acum[mt] = mfma16(lf,  bfa, acum[mt]);
    }
    __syncthreads();
  }

  // ---- phase C: cross numerator Q @ HKpre (8 HK-slices, s=10..17) ----
  #pragma unroll
  for (int ks = 0; ks < 8; ks++) {
    if (ks < 7) stage<256>(hkb + (ks + 1) * 32, 256, ST[(ks + 1) & 1], tid);
    else        stage<64>(abase, 1024, ST[0], tid);       // slice 18: A ks=0
    const __bf16* sl = ST[ks & 1];
    #pragma unroll
    for (int mt = 0; mt < 16; mt++) {
      bf8_t bv = bfrag(sl, mt * 16 + l16, quad);
      aok[mt] = mfma16(aq[ks], bv, aok[mt]);
    }
    __syncthreads();
  }

  // ---- softmax over m ; W = qv / SumA ----
  #pragma unroll
  for (int r = 0; r < 4; r++) {
    float ovv[16], sa[16];
    float mx = -3.0e38f;
    #pragma unroll
    for (int mt = 0; mt < 16; mt++) {
      sa[mt] = zs[mt * 16 + l16] + acum[mt][r];
      ovv[mt] = SCALE * aok[mt][r] / sa[mt];
      mx = fmaxf(mx, ovv[mt]);
    }
    #pragma unroll
    for (int off = 1; off < 16; off <<= 1) mx = fmaxf(mx, __shfl_xor(mx, off));
    float se = 0.f;
    #pragma unroll
    for (int mt = 0; mt < 16; mt++) { ovv[mt] = __expf(ovv[mt] - mx); se += ovv[mt]; }
    #pragma unroll
    for (int off = 1; off < 16; off <<= 1) se += __shfl_xor(se, off);
    float inv = 1.0f / se;
    int tl = wvid * 16 + quad * 4 + r;
    #pragma unroll
    for (int mt = 0; mt < 16; mt++)
      Ws[tl][mt * 16 + l16] = (__bf16)(ovv[mt] * inv / sa[mt]);
  }

  // ---- phase 4a: P = mask(W @ A^T) (8 A-slices, s=18..25) ----
  f4_t pacc[4];
  #pragma unroll
  for (int it = 0; it < 4; it++) pacc[it] = fzero;
  #pragma unroll
  for (int ks = 0; ks < 8; ks++) {
    if (ks < 7) stage<64>(abase + (ks + 1) * 32, 1024, ST[(ks + 1) & 1], tid);
    else        stage<256>(hvb, 256, ST[0], tid);         // slice 26: HV ks=0
    const __bf16* sl = ST[ks & 1];
    bf8_t wf = *reinterpret_cast<const bf8_t*>(&Ws[wvid * 16 + l16][ks * 32 + quad * 8]);
    #pragma unroll
    for (int it = 0; it < 4; it++) {
      bf8_t ba = bfrag(sl, it * 16 + l16, quad);
      pacc[it] = mfma16(wf, ba, pacc[it]);
    }
    __syncthreads();
  }
  #pragma unroll
  for (int it = 0; it < 4; it++)
    #pragma unroll
    for (int r = 0; r < 4; r++) {
      int tl = wvid * 16 + quad * 4 + r;
      int il = it * 16 + l16;
      S1s[tl][il] = (il <= tl) ? (__bf16)pacc[it][r] : (__bf16)0.0f;
    }

  // ---- phase 4b-1: O = W @ HVpre^T (8 HV-slices, s=26..33) ----
  f4_t oacc[16];
  #pragma unroll
  for (int vt = 0; vt < 16; vt++) oacc[vt] = fzero;
  #pragma unroll
  for (int ks = 0; ks < 8; ks++) {
    if (ks < 7) stage<256>(hvb + (ks + 1) * 32, 256, ST[(ks + 1) & 1], tid);
    else        stage<256>(vtb, 64, ST[0], tid);          // slice 34: VT iks=0
    const __bf16* sl = ST[ks & 1];
    bf8_t wf = *reinterpret_cast<const bf8_t*>(&Ws[wvid * 16 + l16][ks * 32 + quad * 8]);
    #pragma unroll
    for (int vt = 0; vt < 16; vt++) {
      bf8_t bv = bfrag(sl, vt * 16 + l16, quad);
      oacc[vt] = mfma16(wf, bv, oacc[vt]);
    }
    __syncthreads();
  }
  // ---- phase 4b-2: O += P @ V (2 VT-slices, s=34..35) ----
  #pragma unroll
  for (int iks = 0; iks < 2; iks++) {
    if (iks == 0) stage<256>(vtb + 32, 64, ST[1], tid);   // slice 35: VT iks=1
    const __bf16* sl = ST[iks & 1];
    bf8_t pf = *reinterpret_cast<const bf8_t*>(&S1s[wvid * 16 + l16][iks * 32 + quad * 8]);
    #pragma unroll
    for (int vt = 0; vt < 16; vt++) {
      bf8_t bvt = bfrag(sl, vt * 16 + l16, quad);
      oacc[vt] = mfma16(pf, bvt, oacc[vt]);
    }
    __syncthreads();
  }

  // ---- epilogue: fused RMSNorm * gn_w * g * sigmoid(g) -> y (bf16) ----
  #pragma unroll
  for (int r = 0; r < 4; r++) {
    float ss = 0.f;
    #pragma unroll
    for (int vt = 0; vt < 16; vt++) ss += oacc[vt][r] * oacc[vt][r];
    #pragma unroll
    for (int off = 1; off < 16; off <<= 1) ss += __shfl_xor(ss, off);
    float rinv = rsqrtf(ss * (1.0f / 256.0f) + EPS);
    int tl = wvid * 16 + quad * 4 + r;
    const __bf16* grow = gg + (R + tl) * 1024 + F;
    __bf16* yrow = yout + (R + tl) * 1024 + F;
    #pragma unroll
    for (int vt = 0; vt < 16; vt++) {
      int v = vt * 16 + l16;
      float gvl = (float)grow[v];
      float yv = oacc[vt][r] * rinv * gns[v] * gvl / (1.0f + __expf(-gvl));
      yrow[v] = (__bf16)yv;
    }
  }
}

// ---------------------------------------------------------------------------
// Workspace layout (MB), peak 253 MB:
//   0-16 q | 16-32 k | 32-48 v -> AT | 48-64 g | 64-80 a | 80-96 xb -> VT
//   96-97 sgl/sgc/csA | 97-161 HKc | 161-225 HVc | 225-237 wt
//   237-253 KT -> y_bf
// ---------------------------------------------------------------------------
extern "C" void kernel_launch(void* const* d_in, const int* in_sizes, int n_in,
                              void* d_out, int out_size, void* d_ws, size_t ws_size,
                              hipStream_t stream) {
  using namespace abc;
  (void)in_sizes; (void)n_in; (void)out_size; (void)ws_size;
  const float* x    = (const float*)d_in[0];
  const float* q_w  = (const float*)d_in[1];
  const float* k_w  = (const float*)d_in[2];
  const float* v_w  = (const float*)d_in[3];
  const float* g_w  = (const float*)d_in[4];
  const float* s_w  = (const float*)d_in[5];
  const float* sg_w = (const float*)d_in[6];
  const float* gn_w = (const float*)d_in[7];
  const float* o_w  = (const float*)d_in[8];
  float* out = (float*)d_out;

  char* ws = (char*)d_ws;
  const size_t PROJ = (size_t)BT * 1024;       // elements per projection
  __bf16* proj = (__bf16*)ws;
  __bf16* q_bf = proj + 0 * PROJ;
  __bf16* k_bf = proj + 1 * PROJ;
  __bf16* v_bf = proj + 2 * PROJ;              // -> AT after transpose1
  __bf16* g_bf = proj + 3 * PROJ;
  __bf16* a_bf = proj + 4 * PROJ;
  __bf16* xb   = proj + 5 * PROJ;              // -> VT after proj gemm
  float* sgl = (float*)(ws + (size_t)96 * 1024 * 1024);
  float* sgc = sgl + (size_t)BH * T;
  float* csA = sgc + (size_t)BH * T;           // 16*32*256 floats
  __bf16* HKc = (__bf16*)(ws + (size_t)97 * 1024 * 1024);   // 64MB
  __bf16* HVc = HKc + (size_t)BH * NC * 65536;               // 64MB
  __bf16* wt  = (__bf16*)(ws + (size_t)225 * 1024 * 1024);  // 12MB
  __bf16* KT  = (__bf16*)(ws + (size_t)237 * 1024 * 1024);  // 16MB
  __bf16* VT  = xb;                            // overlay (xb dead)
  __bf16* AT  = v_bf;                          // overlay (v dead)
  __bf16* y_bf = KT;                           // overlay (KT dead)

  dim3 blk(256);
  cvt_w_kernel<<<dim3(16, 16, 6), blk, 0, stream>>>(q_w, k_w, v_w, g_w, s_w, o_w, wt);
  cvt_x_kernel<<<dim3(BT * 1024 / (256 * 8)), blk, 0, stream>>>(x, xb);
  gemm_bt_kernel<true><<<dim3(8, 64, 5), blk, 0, stream>>>(xb, wt, proj);
  sg_kernel<<<dim3(BT / 4), blk, 0, stream>>>(x, sg_w, sgl);
  scan_kernel<<<dim3(BH), blk, 0, stream>>>(sgl, sgc);
  prep_kernel<<<dim3(BT), blk, 0, stream>>>(q_bf, k_bf, a_bf, sgc);
  transpose_kernel<<<dim3(NC, BH, 2), blk, 0, stream>>>(k_bf, v_bf, KT, VT);
  transpose_kernel<<<dim3(NC, BH, 1), blk, 0, stream>>>(a_bf, a_bf, AT, AT);
  chunkstate_kernel<<<dim3(NC, BH, 4), blk, 0, stream>>>(KT, VT, AT, HKc, HVc, csA);
  prefix_state_kernel<<<dim3(64, BH, 2), blk, 0, stream>>>(HKc, HVc);
  prefix_csa_kernel<<<dim3(BH), blk, 0, stream>>>(csA);
  attn_kernel<<<dim3(NC, BH), blk, 0, stream>>>(
      q_bf, k_bf, a_bf, g_bf, AT, VT, HKc, HVc, csA, gn_w, y_bf);
  gemm_bt_kernel<false><<<dim3(8, 64, 1), blk, 0, stream>>>(
      y_bf, wt + (size_t)5 * 1024 * 1024, out);
}

// Round 7
// 484.884 us; speedup vs baseline: 1.9418x; 1.0360x over previous
//
#include <hip/hip_runtime.h>
#include <hip/hip_bf16.h>
#include <stdint.h>
#include <stddef.h>
#include <math.h>

typedef __bf16 bf8_t __attribute__((ext_vector_type(8)));
typedef __bf16 bf4_t __attribute__((ext_vector_type(4)));
typedef float  f4_t  __attribute__((ext_vector_type(4)));
typedef unsigned int u32;

#define DEV static __device__ __forceinline__

namespace abc {
constexpr int B = 4, T = 2048, D = 1024, H = 4;
constexpr int BT = B * T;          // 8192
constexpr int CH = 64;             // chunk length
constexpr int NC = T / CH;         // 32 chunks
constexpr int BH = B * H;          // 16
constexpr float SCALE = 0.0625f;   // DK^-0.5
constexpr float GN = 16.0f;
constexpr float EPS = 1e-5f;
}

DEV f4_t mfma16(bf8_t a, bf8_t b, f4_t c) {
  return __builtin_amdgcn_mfma_f32_16x16x32_bf16(a, b, c, 0, 0, 0);
}

// async global->LDS, 16B per lane; lds dest must be wave-uniform base (+lane*16)
DEV void glds16(const void* g, void* l) {
  __builtin_amdgcn_global_load_lds(
      (const __attribute__((address_space(1))) u32*)g,
      (__attribute__((address_space(3))) u32*)l, 16, 0, 0);
}

// stage a ROWSx32col bf16 slice into LDS, group-XOR-swizzled on the GLOBAL
// gather side: LDS 16B-group p holds global (row m=p>>2, colgrp (p&3)^(m&3)).
template<int ROWS>
DEV void stage(const __bf16* __restrict__ g, int S /*elem row stride*/,
               __bf16* lds, int tid) {
  #pragma unroll
  for (int i = 0; i < ROWS / 64; i++) {
    int p = i * 256 + tid;
    int m = p >> 2;
    int q = (p & 3) ^ (m & 3);
    glds16(g + (size_t)m * S + q * 8, lds + (i * 256 + (tid & ~63)) * 8);
  }
}
// read B-fragment (row m, k-group quad) from a staged slice
DEV bf8_t bfrag(const __bf16* sl, int m, int quad) {
  return *reinterpret_cast<const bf8_t*>(sl + m * 32 + ((quad ^ (m & 3)) << 3));
}

// ---------------------------------------------------------------------------
// x fp32 -> bf16 (row-major unchanged). 8 elems/thread.
// ---------------------------------------------------------------------------
__global__ __launch_bounds__(256)
void cvt_x_kernel(const float* __restrict__ x, __bf16* __restrict__ xb)
{
  const int idx = blockIdx.x * 256 + threadIdx.x;   // 1M threads total
  const float4* src = reinterpret_cast<const float4*>(x);
  float4 a = src[(size_t)idx * 2];
  float4 b = src[(size_t)idx * 2 + 1];
  bf8_t o;
  o[0] = (__bf16)a.x; o[1] = (__bf16)a.y; o[2] = (__bf16)a.z; o[3] = (__bf16)a.w;
  o[4] = (__bf16)b.x; o[5] = (__bf16)b.y; o[6] = (__bf16)b.z; o[7] = (__bf16)b.w;
  reinterpret_cast<bf8_t*>(xb)[idx] = o;
}

// ---------------------------------------------------------------------------
// weight fp32 [k][n] -> bf16 [n][k] (transpose), 64x64 tiles, 6 weights
// ---------------------------------------------------------------------------
__global__ __launch_bounds__(256)
void cvt_w_kernel(const float* __restrict__ w0, const float* __restrict__ w1,
                  const float* __restrict__ w2, const float* __restrict__ w3,
                  const float* __restrict__ w4, const float* __restrict__ w5,
                  __bf16* __restrict__ wt)
{
  const int z = blockIdx.z;
  const float* W = (z == 0) ? w0 : (z == 1) ? w1 : (z == 2) ? w2
                 : (z == 3) ? w3 : (z == 4) ? w4 : w5;
  const int n0 = blockIdx.x * 64, k0 = blockIdx.y * 64;
  __shared__ __bf16 Ts[64][72];
  const int tid = threadIdx.x;
  #pragma unroll
  for (int i = 0; i < 4; i++) {
    int p = tid + 256 * i;            // 1024 float4 chunks: 64 k-rows x 16
    int row = p >> 4, c4 = p & 15;
    float4 v = *reinterpret_cast<const float4*>(W + (size_t)(k0 + row) * 1024 + n0 + c4 * 4);
    Ts[c4 * 4 + 0][row] = (__bf16)v.x;
    Ts[c4 * 4 + 1][row] = (__bf16)v.y;
    Ts[c4 * 4 + 2][row] = (__bf16)v.z;
    Ts[c4 * 4 + 3][row] = (__bf16)v.w;
  }
  __syncthreads();
  #pragma unroll
  for (int i = 0; i < 2; i++) {
    int p = tid + 256 * i;            // 512 bf8 chunks: 64 n-rows x 8
    int n = p >> 3, kq = p & 7;
    bf8_t o = *reinterpret_cast<const bf8_t*>(&Ts[n][kq * 8]);
    *reinterpret_cast<bf8_t*>(wt + (size_t)z * 1024 * 1024 + (size_t)(n0 + n) * 1024 + k0 + kq * 8) = o;
  }
}

// ---------------------------------------------------------------------------
// m97-style GEMM: C[8192 x 1024] = A[8192 x 1024] * Bt[z][n][k]^T
// 1-D grid, XCD-aware swizzle: XCD = m-group so the ~40 co-resident blocks
// per XCD share one 256KB A-tile in L2 (A read once from HBM, total).
// ---------------------------------------------------------------------------
template<bool OUT_BF16, int NZ>
__global__ __launch_bounds__(256)
void gemm_bt_kernel(const __bf16* __restrict__ A, const __bf16* __restrict__ BtB,
                    void* __restrict__ Cp)
{
  using namespace abc;
  constexpr int K = 1024;
  constexpr int NZC = 8 * NZ;              // (n,z) combos per m-tile
  const int bflat = blockIdx.x;            // 64*8*NZ blocks
  const int xcd = bflat & 7;
  const int j = bflat >> 3;                // per-XCD work index
  const int m_local = j / NZC;             // 0..7
  const int nz = j % NZC;
  const int nt = nz & 7, z = nz >> 3;
  const int m0 = (xcd * 8 + m_local) * 128;
  const int n0 = nt * 128;
  const __bf16* Bt = BtB + (size_t)z * K * 1024;
  __shared__ __bf16 As[128 * 64];   // [m][k], unpadded (global_load_lds layout)
  __shared__ __bf16 Bs[128 * 64];   // [n][k]
  const int tid = threadIdx.x;
  const int lane = tid & 63, wvid = tid >> 6;
  const int wr = wvid >> 1, wc = wvid & 1;
  const int quad = lane >> 4, l16 = lane & 15;
  const f4_t fzero = {0.f, 0.f, 0.f, 0.f};
  f4_t acc[4][4];
  #pragma unroll
  for (int i = 0; i < 4; i++)
    #pragma unroll
    for (int j2 = 0; j2 < 4; j2++) acc[i][j2] = fzero;

  const int chunk_row = tid >> 3;
  const int chunk_col = tid & 7;
  for (int k0 = 0; k0 < K; k0 += 64) {
    __syncthreads();
    #pragma unroll
    for (int i = 0; i < 4; i++) {
      glds16(A + (size_t)(m0 + i * 32 + chunk_row) * K + k0 + chunk_col * 8,
             &As[(size_t)(i * 256 + wvid * 64) * 8]);
    }
    #pragma unroll
    for (int i = 0; i < 4; i++) {
      glds16(Bt + (size_t)(n0 + i * 32 + chunk_row) * K + k0 + chunk_col * 8,
             &Bs[(size_t)(i * 256 + wvid * 64) * 8]);
    }
    __syncthreads();
    #pragma unroll
    for (int ks = 0; ks < 2; ks++) {
      bf8_t af[4], bfv[4];
      #pragma unroll
      for (int i = 0; i < 4; i++)
        af[i] = *reinterpret_cast<const bf8_t*>(
            &As[(size_t)(wr * 64 + i * 16 + l16) * 64 + ks * 32 + quad * 8]);
      #pragma unroll
      for (int j2 = 0; j2 < 4; j2++)
        bfv[j2] = *reinterpret_cast<const bf8_t*>(
            &Bs[(size_t)(wc * 64 + j2 * 16 + l16) * 64 + ks * 32 + quad * 8]);
      #pragma unroll
      for (int i = 0; i < 4; i++)
        #pragma unroll
        for (int j2 = 0; j2 < 4; j2++)
          acc[i][j2] = mfma16(af[i], bfv[j2], acc[i][j2]);
    }
  }
  const int crow = m0 + wr * 64, ccol = n0 + wc * 64;
  if (OUT_BF16) {
    __bf16* C = (__bf16*)Cp + (size_t)z * BT * 1024;
    #pragma unroll
    for (int i = 0; i < 4; i++)
      #pragma unroll
      for (int j2 = 0; j2 < 4; j2++)
        #pragma unroll
        for (int r = 0; r < 4; r++)
          C[(size_t)(crow + i * 16 + quad * 4 + r) * 1024 + ccol + j2 * 16 + l16] =
              (__bf16)acc[i][j2][r];
  } else {
    float* C = (float*)Cp;
    #pragma unroll
    for (int i = 0; i < 4; i++)
      #pragma unroll
      for (int j2 = 0; j2 < 4; j2++)
        #pragma unroll
        for (int r = 0; r < 4; r++)
          C[(size_t)(crow + i * 16 + quad * 4 + r) * 1024 + ccol + j2 * 16 + l16] =
              acc[i][j2][r];
  }
}

// ---------------------------------------------------------------------------
// sg projection
// ---------------------------------------------------------------------------
__global__ __launch_bounds__(256)
void sg_kernel(const float* __restrict__ x, const float* __restrict__ sgw,
               float* __restrict__ sgl)
{
  using namespace abc;
  const int wvid = threadIdx.x >> 6, lane = threadIdx.x & 63;
  const int bt = blockIdx.x * 4 + wvid;
  const float* xr = x + (size_t)bt * 1024;
  float a0 = 0, a1 = 0, a2 = 0, a3 = 0;
  #pragma unroll 4
  for (int u = 0; u < 16; u++) {
    int i = u * 64 + lane;
    float xv = xr[i];
    float4 w = *reinterpret_cast<const float4*>(sgw + (size_t)i * 4);
    a0 += xv * w.x; a1 += xv * w.y; a2 += xv * w.z; a3 += xv * w.w;
  }
  #pragma unroll
  for (int off = 32; off > 0; off >>= 1) {
    a0 += __shfl_down(a0, off);
    a1 += __shfl_down(a1, off);
    a2 += __shfl_down(a2, off);
    a3 += __shfl_down(a3, off);
  }
  if (lane == 0) {
    const int b = bt >> 11, t = bt & (T - 1);
    float r[4] = {a0, a1, a2, a3};
    #pragma unroll
    for (int h = 0; h < 4; h++) {
      float v = r[h];
      float ls = fminf(v, 0.f) - log1pf(expf(-fabsf(v)));
      sgl[(size_t)(b * 4 + h) * T + t] = ls * (1.0f / GN);
    }
  }
}

// ---------------------------------------------------------------------------
// inclusive cumsum over T per (b,h)
// ---------------------------------------------------------------------------
__global__ __launch_bounds__(256)
void scan_kernel(const float* __restrict__ sgl, float* __restrict__ sgc)
{
  using namespace abc;
  const int bh = blockIdx.x;
  const float* in = sgl + (size_t)bh * T;
  float* out = sgc + (size_t)bh * T;
  __shared__ float part[256];
  const int tid = threadIdx.x;
  float v[8]; float s = 0.f;
  #pragma unroll
  for (int i = 0; i < 8; i++) { v[i] = in[tid * 8 + i]; s += v[i]; }
  part[tid] = s;
  __syncthreads();
  for (int off = 1; off < 256; off <<= 1) {
    float a = (tid >= off) ? part[tid - off] : 0.f;
    __syncthreads();
    part[tid] += a;
    __syncthreads();
  }
  float run = (tid > 0) ? part[tid - 1] : 0.f;
  #pragma unroll
  for (int i = 0; i < 8; i++) { run += v[i]; out[tid * 8 + i] = run; }
}

// ---------------------------------------------------------------------------
// prep: RoPE(q), RoPE(k)*exp(cumsum sg), s -> exp(clamp(s)) ; in-place on bf16
// ---------------------------------------------------------------------------
__global__ __launch_bounds__(256)
void prep_kernel(__bf16* __restrict__ q, __bf16* __restrict__ k,
                 __bf16* __restrict__ s, const float* __restrict__ sgc)
{
  using namespace abc;
  const int bt = blockIdx.x;
  const int b = bt >> 11, t = bt & (T - 1);
  const int tid = threadIdx.x;
  const size_t ro = (size_t)bt * 1024;
  #pragma unroll
  for (int i = 0; i < 2; i++) {
    int p = tid + 256 * i;          // 0..511 : h = p/128, d = p%128
    int h = p >> 7, d = p & 127;
    float inv = expf(-(float)d * (9.210340371976184f / 128.0f)); // 10000^(-d/128)
    float ang = (float)t * inv;
    float sn, cs;
    sincosf(ang, &sn, &cs);
    size_t base = ro + (size_t)h * 256 + d;
    float q1 = (float)q[base], q2 = (float)q[base + 128];
    q[base]       = (__bf16)(q1 * cs - q2 * sn);
    q[base + 128] = (__bf16)(q2 * cs + q1 * sn);
    float dec = expf(sgc[(size_t)(b * 4 + h) * T + t]);
    float k1 = (float)k[base], k2 = (float)k[base + 128];
    k[base]       = (__bf16)((k1 * cs - k2 * sn) * dec);
    k[base + 128] = (__bf16)((k2 * cs + k1 * sn) * dec);
  }
  #pragma unroll
  for (int i = 0; i < 4; i++) {
    int e = tid + 256 * i;
    float v = (float)s[ro + e];
    v = fminf(fmaxf(v, -32.f), 32.f);
    s[ro + e] = (__bf16)expf(v);
  }
}

// ---------------------------------------------------------------------------
// transpose chunks: [t=64][f=256] -> [bh][c][f=256][t=64]; up to 2 srcs per
// launch (blockIdx.z). LDS XOR-swizzled.
// ---------------------------------------------------------------------------
__global__ __launch_bounds__(256)
void transpose_kernel(const __bf16* __restrict__ s0, const __bf16* __restrict__ s1,
                      __bf16* __restrict__ d0, __bf16* __restrict__ d1)
{
  using namespace abc;
  const int c = blockIdx.x, bh = blockIdx.y, z = blockIdx.z;
  const int b = bh >> 2, h = bh & 3;
  const size_t R = (size_t)b * T + (size_t)c * CH;
  const int F = h * 256;
  const __bf16* src = z ? s1 : s0;
  __bf16* dst = (z ? d1 : d0) + ((size_t)bh * NC + c) * (256 * 64);
  __shared__ __bf16 L[256 * 64];
  const int tid = threadIdx.x;
  #pragma unroll
  for (int j = 0; j < 8; j++) {
    int p = tid + 256 * j;            // (t = p>>5, fc = p&31)
    int t = p >> 5, fc = p & 31;
    bf8_t v = *reinterpret_cast<const bf8_t*>(src + (R + t) * 1024 + F + fc * 8);
    const int sw = ((t >> 3) ^ (fc & 7)) * 8 + (t & 7);
    #pragma unroll
    for (int u = 0; u < 8; u++)
      L[(fc * 8 + u) * 64 + sw] = v[u];
  }
  __syncthreads();
  #pragma unroll
  for (int j = 0; j < 8; j++) {
    int p = tid + 256 * j;            // (f = p>>3, q = p&7)
    int f = p >> 3, q = p & 7;
    int phys = q ^ ((f >> 3) & 7);
    bf8_t o = *reinterpret_cast<const bf8_t*>(&L[f * 64 + phys * 8]);
    *reinterpret_cast<bf8_t*>(dst + (size_t)f * 64 + q * 8) = o;
  }
}

// ---------------------------------------------------------------------------
// per-chunk states (no LDS; fragments straight from global KT/VT/AT):
// ---------------------------------------------------------------------------
__global__ __launch_bounds__(256)
void chunkstate_kernel(const __bf16* __restrict__ KT, const __bf16* __restrict__ VT,
                       const __bf16* __restrict__ AT,
                       __bf16* __restrict__ HKc, __bf16* __restrict__ HVc,
                       float* __restrict__ csA)
{
  using namespace abc;
  const int c = blockIdx.x, bh = blockIdx.y, part = blockIdx.z;
  const size_t TB = ((size_t)bh * NC + c) * (256 * 64);
  const bool isHV = part >= 2;
  const int p2 = part & 1;
  const __bf16* Aop = (isHV ? VT : AT) + TB;   // rows = out-dim (v or m)
  const __bf16* Bop = (isHV ? AT : KT) + TB;   // rows = out-col  (m or k)
  const int tid = threadIdx.x;
  if (part == 2) {
    float ssum = 0.f;
    #pragma unroll
    for (int u = 0; u < 8; u++) {
      bf8_t v = *reinterpret_cast<const bf8_t*>(AT + TB + (size_t)tid * 64 + u * 8);
      #pragma unroll
      for (int w = 0; w < 8; w++) ssum += (float)v[w];
    }
    csA[((size_t)bh * NC + c) * 256 + tid] = ssum;
  }
  const int lane = tid & 63, wvid = tid >> 6;
  const int quad = lane >> 4, l16 = lane & 15;
  const int row0 = p2 * 128 + wvid * 32;
  const f4_t fzero = {0.f, 0.f, 0.f, 0.f};
  f4_t acc[2][16];
  #pragma unroll
  for (int a = 0; a < 2; a++)
    #pragma unroll
    for (int ct = 0; ct < 16; ct++) acc[a][ct] = fzero;
  #pragma unroll
  for (int ks = 0; ks < 2; ks++) {
    bf8_t af0 = *reinterpret_cast<const bf8_t*>(Aop + (size_t)(row0 + l16) * 64 + ks * 32 + quad * 8);
    bf8_t af1 = *reinterpret_cast<const bf8_t*>(Aop + (size_t)(row0 + 16 + l16) * 64 + ks * 32 + quad * 8);
    #pragma unroll
    for (int ct = 0; ct < 16; ct++) {
      bf8_t bv = *reinterpret_cast<const bf8_t*>(Bop + (size_t)(ct * 16 + l16) * 64 + ks * 32 + quad * 8);
      acc[0][ct] = mfma16(af0, bv, acc[0][ct]);
      acc[1][ct] = mfma16(af1, bv, acc[1][ct]);
    }
  }
  __bf16* out = (isHV ? HVc : HKc) + ((size_t)bh * NC + c) * 65536;
  #pragma unroll
  for (int rt = 0; rt < 2; rt++)
    #pragma unroll
    for (int ct = 0; ct < 16; ct++)
      #pragma unroll
      for (int r = 0; r < 4; r++)
        out[(size_t)(row0 + rt * 16 + quad * 4 + r) * 256 + ct * 16 + l16] =
            (__bf16)acc[rt][ct][r];
}

// ---------------------------------------------------------------------------
// in-place exclusive prefix over chunk axis of HKc/HVc (bf16, fp32 run)
// ---------------------------------------------------------------------------
__global__ __launch_bounds__(256)
void prefix_state_kernel(__bf16* __restrict__ HKc, __bf16* __restrict__ HVc)
{
  using namespace abc;
  const int bh = blockIdx.y;
  __bf16* base = (blockIdx.z ? HVc : HKc) + (size_t)bh * NC * 65536;
  const int e = (blockIdx.x * 256 + threadIdx.x) * 4;
  float run0 = 0, run1 = 0, run2 = 0, run3 = 0;
  for (int c = 0; c < NC; c++) {
    __bf16* p = base + (size_t)c * 65536 + e;
    bf4_t v = *reinterpret_cast<const bf4_t*>(p);
    bf4_t o;
    o[0] = (__bf16)run0; o[1] = (__bf16)run1; o[2] = (__bf16)run2; o[3] = (__bf16)run3;
    run0 += (float)v[0]; run1 += (float)v[1]; run2 += (float)v[2]; run3 += (float)v[3];
    *reinterpret_cast<bf4_t*>(p) = o;
  }
}

__global__ __launch_bounds__(256)
void prefix_csa_kernel(float* __restrict__ csA)
{
  using namespace abc;
  const int bh = blockIdx.x, m = threadIdx.x;
  float run = 0.f;
  for (int c = 0; c < NC; c++) {
    float* p = csA + ((size_t)bh * NC + c) * 256 + m;
    float v = *p; *p = run; run += v;
  }
}

// ---------------------------------------------------------------------------
// main chunked ABC attention + fused RMSNorm/SiLU-gate epilogue
// one block per (chunk, bh). Shared B-operands (K, AT, HK, A, HV, VT) stream
// through a 2x16KB double-buffered LDS ring via global_load_lds (36 slices,
// group-XOR swizzle folded into the global gather). LDS 76 KB -> 2 blocks/CU.
// ---------------------------------------------------------------------------
__global__ __launch_bounds__(256)
void attn_kernel(const __bf16* __restrict__ qg, const __bf16* __restrict__ kg,
                 const __bf16* __restrict__ ag, const __bf16* __restrict__ gg,
                 const __bf16* __restrict__ ATp, const __bf16* __restrict__ VTp,
                 const __bf16* __restrict__ HKp, const __bf16* __restrict__ HVp,
                 const float* __restrict__ Zp, const float* __restrict__ gnw,
                 __bf16* __restrict__ yout)
{
  using namespace abc;
  const int c = blockIdx.x, bh = blockIdx.y;
  const int b = bh >> 2, h = bh & 3;
  const size_t R = (size_t)b * T + (size_t)c * CH;
  const int F = h * 256;
  const int tid = threadIdx.x;
  const int lane = tid & 63, wvid = tid >> 6;
  const int quad = lane >> 4, l16 = lane & 15;

  __shared__ __bf16 ST[2][8192];   // staging ring, 2 x 16 KB
  __shared__ __bf16 Ws[64][264];   // W = qv / SumA (per-wave strip)
  __shared__ __bf16 S1s[64][72];   // masked QK^T, later masked P (per-wave strip)
  __shared__ float zs[256];
  __shared__ float gns[256];

  const __bf16* atb = ATp + ((size_t)bh * NC + c) * (256 * 64);
  const __bf16* vtb = VTp + ((size_t)bh * NC + c) * (256 * 64);
  const __bf16* hkb = HKp + ((size_t)bh * NC + c) * 65536;
  const __bf16* hvb = HVp + ((size_t)bh * NC + c) * 65536;
  const __bf16* kbase = kg + R * 1024 + F;
  const __bf16* abase = ag + R * 1024 + F;

  zs[tid] = Zp[((size_t)bh * NC + c) * 256 + tid];
  gns[tid] = gnw[tid];

  // preload Q fragments (row = own strip row, all 8 k-groups)
  const __bf16* qrow = qg + (R + wvid * 16 + l16) * 1024 + F;
  bf8_t aq[8];
  #pragma unroll
  for (int ks = 0; ks < 8; ks++)
    aq[ks] = *reinterpret_cast<const bf8_t*>(qrow + ks * 32 + quad * 8);

  const f4_t fzero = {0.f, 0.f, 0.f, 0.f};

  // slice pipeline: s = 0..35 ; buffer = s&1
  stage<64>(kbase, 1024, ST[0], tid);               // slice 0: K ks=0
  __syncthreads();

  // ---- phase A: S1 = Q K^T (8 K-slices, s=0..7) ----
  f4_t s1a[4];
  #pragma unroll
  for (int it = 0; it < 4; it++) s1a[it] = fzero;
  #pragma unroll
  for (int ks = 0; ks < 8; ks++) {
    if (ks < 7) stage<64>(kbase + (ks + 1) * 32, 1024, ST[(ks + 1) & 1], tid);
    else        stage<256>(atb, 64, ST[0], tid);    // slice 8: AT iks=0
    const __bf16* sl = ST[ks & 1];
    #pragma unroll
    for (int it = 0; it < 4; it++) {
      bf8_t bk = bfrag(sl, it * 16 + l16, quad);
      s1a[it] = mfma16(aq[ks], bk, s1a[it]);
    }
    __syncthreads();
  }
  #pragma unroll
  for (int it = 0; it < 4; it++)
    #pragma unroll
    for (int r = 0; r < 4; r++) {
      int tl = wvid * 16 + quad * 4 + r;
      int il = it * 16 + l16;
      S1s[tl][il] = (il <= tl) ? (__bf16)s1a[it][r] : (__bf16)0.0f;
    }

  // ---- phase B: intra numerator + cumA (2 AT-slices, s=8..9) ----
  f4_t aok[16], acum[16];
  #pragma unroll
  for (int mt = 0; mt < 16; mt++) { aok[mt] = fzero; acum[mt] = fzero; }
  #pragma unroll
  for (int iks = 0; iks < 2; iks++) {
    if (iks == 0) stage<256>(atb + 32, 64, ST[1], tid);   // slice 9: AT iks=1
    else          stage<256>(hkb, 256, ST[0], tid);       // slice 10: HK ks=0
    const __bf16* sl = ST[iks & 1];
    bf8_t s1f = *reinterpret_cast<const bf8_t*>(&S1s[wvid * 16 + l16][iks * 32 + quad * 8]);
    bf8_t lf;
    #pragma unroll
    for (int j = 0; j < 8; j++)
      lf[j] = (iks * 32 + quad * 8 + j <= wvid * 16 + l16) ? (__bf16)1.0f : (__bf16)0.0f;
    #pragma unroll
    for (int mt = 0; mt < 16; mt++) {
      bf8_t bfa = bfrag(sl, mt * 16 + l16, quad);
      aok[mt]  = mfma16(s1f, bfa, aok[mt]);
      acum[mt] = mfma16(lf,  bfa, acum[mt]);
    }
    __syncthreads();
  }

  // ---- phase C: cross numerator Q @ HKpre (8 HK-slices, s=10..17) ----
  #pragma unroll
  for (int ks = 0; ks < 8; ks++) {
    if (ks < 7) stage<256>(hkb + (ks + 1) * 32, 256, ST[(ks + 1) & 1], tid);
    else        stage<64>(abase, 1024, ST[0], tid);       // slice 18: A ks=0
    const __bf16* sl = ST[ks & 1];
    #pragma unroll
    for (int mt = 0; mt < 16; mt++) {
      bf8_t bv = bfrag(sl, mt * 16 + l16, quad);
      aok[mt] = mfma16(aq[ks], bv, aok[mt]);
    }
    __syncthreads();
  }

  // ---- softmax over m ; W = qv / SumA ----
  #pragma unroll
  for (int r = 0; r < 4; r++) {
    float ovv[16], sa[16];
    float mx = -3.0e38f;
    #pragma unroll
    for (int mt = 0; mt < 16; mt++) {
      sa[mt] = zs[mt * 16 + l16] + acum[mt][r];
      ovv[mt] = SCALE * aok[mt][r] / sa[mt];
      mx = fmaxf(mx, ovv[mt]);
    }
    #pragma unroll
    for (int off = 1; off < 16; off <<= 1) mx = fmaxf(mx, __shfl_xor(mx, off));
    float se = 0.f;
    #pragma unroll
    for (int mt = 0; mt < 16; mt++) { ovv[mt] = __expf(ovv[mt] - mx); se += ovv[mt]; }
    #pragma unroll
    for (int off = 1; off < 16; off <<= 1) se += __shfl_xor(se, off);
    float inv = 1.0f / se;
    int tl = wvid * 16 + quad * 4 + r;
    #pragma unroll
    for (int mt = 0; mt < 16; mt++)
      Ws[tl][mt * 16 + l16] = (__bf16)(ovv[mt] * inv / sa[mt]);
  }

  // ---- phase 4a: P = mask(W @ A^T) (8 A-slices, s=18..25) ----
  f4_t pacc[4];
  #pragma unroll
  for (int it = 0; it < 4; it++) pacc[it] = fzero;
  #pragma unroll
  for (int ks = 0; ks < 8; ks++) {
    if (ks < 7) stage<64>(abase + (ks + 1) * 32, 1024, ST[(ks + 1) & 1], tid);
    else        stage<256>(hvb, 256, ST[0], tid);         // slice 26: HV ks=0
    const __bf16* sl = ST[ks & 1];
    bf8_t wf = *reinterpret_cast<const bf8_t*>(&Ws[wvid * 16 + l16][ks * 32 + quad * 8]);
    #pragma unroll
    for (int it = 0; it < 4; it++) {
      bf8_t ba = bfrag(sl, it * 16 + l16, quad);
      pacc[it] = mfma16(wf, ba, pacc[it]);
    }
    __syncthreads();
  }
  #pragma unroll
  for (int it = 0; it < 4; it++)
    #pragma unroll
    for (int r = 0; r < 4; r++) {
      int tl = wvid * 16 + quad * 4 + r;
      int il = it * 16 + l16;
      S1s[tl][il] = (il <= tl) ? (__bf16)pacc[it][r] : (__bf16)0.0f;
    }

  // ---- phase 4b-1: O = W @ HVpre^T (8 HV-slices, s=26..33) ----
  f4_t oacc[16];
  #pragma unroll
  for (int vt = 0; vt < 16; vt++) oacc[vt] = fzero;
  #pragma unroll
  for (int ks = 0; ks < 8; ks++) {
    if (ks < 7) stage<256>(hvb + (ks + 1) * 32, 256, ST[(ks + 1) & 1], tid);
    else        stage<256>(vtb, 64, ST[0], tid);          // slice 34: VT iks=0
    const __bf16* sl = ST[ks & 1];
    bf8_t wf = *reinterpret_cast<const bf8_t*>(&Ws[wvid * 16 + l16][ks * 32 + quad * 8]);
    #pragma unroll
    for (int vt = 0; vt < 16; vt++) {
      bf8_t bv = bfrag(sl, vt * 16 + l16, quad);
      oacc[vt] = mfma16(wf, bv, oacc[vt]);
    }
    __syncthreads();
  }
  // ---- phase 4b-2: O += P @ V (2 VT-slices, s=34..35) ----
  #pragma unroll
  for (int iks = 0; iks < 2; iks++) {
    if (iks == 0) stage<256>(vtb + 32, 64, ST[1], tid);   // slice 35: VT iks=1
    const __bf16* sl = ST[iks & 1];
    bf8_t pf = *reinterpret_cast<const bf8_t*>(&S1s[wvid * 16 + l16][iks * 32 + quad * 8]);
    #pragma unroll
    for (int vt = 0; vt < 16; vt++) {
      bf8_t bvt = bfrag(sl, vt * 16 + l16, quad);
      oacc[vt] = mfma16(pf, bvt, oacc[vt]);
    }
    __syncthreads();
  }

  // ---- epilogue: fused RMSNorm * gn_w * g * sigmoid(g) -> y (bf16) ----
  #pragma unroll
  for (int r = 0; r < 4; r++) {
    float ss = 0.f;
    #pragma unroll
    for (int vt = 0; vt < 16; vt++) ss += oacc[vt][r] * oacc[vt][r];
    #pragma unroll
    for (int off = 1; off < 16; off <<= 1) ss += __shfl_xor(ss, off);
    float rinv = rsqrtf(ss * (1.0f / 256.0f) + EPS);
    int tl = wvid * 16 + quad * 4 + r;
    const __bf16* grow = gg + (R + tl) * 1024 + F;
    __bf16* yrow = yout + (R + tl) * 1024 + F;
    #pragma unroll
    for (int vt = 0; vt < 16; vt++) {
      int v = vt * 16 + l16;
      float gvl = (float)grow[v];
      float yv = oacc[vt][r] * rinv * gns[v] * gvl / (1.0f + __expf(-gvl));
      yrow[v] = (__bf16)yv;
    }
  }
}

// ---------------------------------------------------------------------------
// Workspace layout (MB), peak 253 MB:
//   0-16 q | 16-32 k | 32-48 v -> AT | 48-64 g | 64-80 a | 80-96 xb -> VT
//   96-97 sgl/sgc/csA | 97-161 HKc | 161-225 HVc | 225-237 wt
//   237-253 KT -> y_bf
// ---------------------------------------------------------------------------
extern "C" void kernel_launch(void* const* d_in, const int* in_sizes, int n_in,
                              void* d_out, int out_size, void* d_ws, size_t ws_size,
                              hipStream_t stream) {
  using namespace abc;
  (void)in_sizes; (void)n_in; (void)out_size; (void)ws_size;
  const float* x    = (const float*)d_in[0];
  const float* q_w  = (const float*)d_in[1];
  const float* k_w  = (const float*)d_in[2];
  const float* v_w  = (const float*)d_in[3];
  const float* g_w  = (const float*)d_in[4];
  const float* s_w  = (const float*)d_in[5];
  const float* sg_w = (const float*)d_in[6];
  const float* gn_w = (const float*)d_in[7];
  const float* o_w  = (const float*)d_in[8];
  float* out = (float*)d_out;

  char* ws = (char*)d_ws;
  const size_t PROJ = (size_t)BT * 1024;       // elements per projection
  __bf16* proj = (__bf16*)ws;
  __bf16* q_bf = proj + 0 * PROJ;
  __bf16* k_bf = proj + 1 * PROJ;
  __bf16* v_bf = proj + 2 * PROJ;              // -> AT after transpose1
  __bf16* g_bf = proj + 3 * PROJ;
  __bf16* a_bf = proj + 4 * PROJ;
  __bf16* xb   = proj + 5 * PROJ;              // -> VT after proj gemm
  float* sgl = (float*)(ws + (size_t)96 * 1024 * 1024);
  float* sgc = sgl + (size_t)BH * T;
  float* csA = sgc + (size_t)BH * T;           // 16*32*256 floats
  __bf16* HKc = (__bf16*)(ws + (size_t)97 * 1024 * 1024);   // 64MB
  __bf16* HVc = HKc + (size_t)BH * NC * 65536;               // 64MB
  __bf16* wt  = (__bf16*)(ws + (size_t)225 * 1024 * 1024);  // 12MB
  __bf16* KT  = (__bf16*)(ws + (size_t)237 * 1024 * 1024);  // 16MB
  __bf16* VT  = xb;                            // overlay (xb dead)
  __bf16* AT  = v_bf;                          // overlay (v dead)
  __bf16* y_bf = KT;                           // overlay (KT dead)

  dim3 blk(256);
  cvt_w_kernel<<<dim3(16, 16, 6), blk, 0, stream>>>(q_w, k_w, v_w, g_w, s_w, o_w, wt);
  cvt_x_kernel<<<dim3(BT * 1024 / (256 * 8)), blk, 0, stream>>>(x, xb);
  gemm_bt_kernel<true, 5><<<dim3(64 * 8 * 5), blk, 0, stream>>>(xb, wt, proj);
  sg_kernel<<<dim3(BT / 4), blk, 0, stream>>>(x, sg_w, sgl);
  scan_kernel<<<dim3(BH), blk, 0, stream>>>(sgl, sgc);
  prep_kernel<<<dim3(BT), blk, 0, stream>>>(q_bf, k_bf, a_bf, sgc);
  transpose_kernel<<<dim3(NC, BH, 2), blk, 0, stream>>>(k_bf, v_bf, KT, VT);
  transpose_kernel<<<dim3(NC, BH, 1), blk, 0, stream>>>(a_bf, a_bf, AT, AT);
  chunkstate_kernel<<<dim3(NC, BH, 4), blk, 0, stream>>>(KT, VT, AT, HKc, HVc, csA);
  prefix_state_kernel<<<dim3(64, BH, 2), blk, 0, stream>>>(HKc, HVc);
  prefix_csa_kernel<<<dim3(BH), blk, 0, stream>>>(csA);
  attn_kernel<<<dim3(NC, BH), blk, 0, stream>>>(
      q_bf, k_bf, a_bf, g_bf, AT, VT, HKc, HVc, csA, gn_w, y_bf);
  gemm_bt_kernel<false, 1><<<dim3(64 * 8), blk, 0, stream>>>(
      y_bf, wt + (size_t)5 * 1024 * 1024, out);
}